// Round 1
// baseline (2276.530 us; speedup 1.0000x reference)
//
#include <hip/hip_runtime.h>

#define MT 4096      // tokens = N*H*W = 4*32*32
#define DM 64        // d_model
#define NHEAD 8
#define HDIM 8
#define DFF 256
#define NLAYER 4
#define LN_EPS 1e-5f

__device__ __forceinline__ float wave_sum64(float v) {
#pragma unroll
  for (int m = 1; m < 64; m <<= 1) v += __shfl_xor(v, m, 64);
  return v;
}

// ---------------------------------------------------------------- copy x <- hsi
__global__ void copy_kernel(const float4* __restrict__ in, float4* __restrict__ out, int n4) {
  int i = blockIdx.x * blockDim.x + threadIdx.x;
  if (i < n4) out[i] = in[i];
}

// ---------------------------------------------------------------- qkv = x @ W^T + b
// one block per token, 192 threads (one per output feature)
__global__ void qkv_kernel(const float* __restrict__ x, const float* __restrict__ W,
                           const float* __restrict__ B, float* __restrict__ qkv) {
  const int t = blockIdx.x;
  const int o = threadIdx.x;
  __shared__ float xr[DM];
  if (o < DM) xr[o] = x[(size_t)t * DM + o];
  __syncthreads();
  const float* w = W + (size_t)o * DM;
  float acc = B[o];
#pragma unroll
  for (int k = 0; k < DM; ++k) acc += xr[k] * w[k];
  qkv[(size_t)t * 192 + o] = acc;
}

// ---------------------------------------------------------------- attention
// grid (MT/32, NHEAD), block 64. lane = tid&31 -> query, half = tid>>5 -> key half.
// two-pass softmax (global max, then exp-sum + PV), K/V tiles of 256 in LDS.
__global__ __launch_bounds__(64) void attn_kernel(const float* __restrict__ qkv,
                                                  float* __restrict__ o_out) {
  const int h = blockIdx.y;
  const int qb = blockIdx.x * 32;
  const int tid = threadIdx.x;
  const int lane = tid & 31;
  const int half = tid >> 5;
  const int tok = qb + lane;

  float q[8];
  const float* qp = qkv + (size_t)tok * 192 + h * HDIM;
#pragma unroll
  for (int j = 0; j < 8; ++j) q[j] = qp[j] * 0.35355339059327373f;  // 1/sqrt(8)

  __shared__ float kt[256 * 8];
  __shared__ float vt[256 * 8];

  // phase 1: global max
  float mmax = -1e30f;
  for (int kb = 0; kb < MT; kb += 256) {
    __syncthreads();
    for (int idx = tid; idx < 2048; idx += 64) {
      int r = idx >> 3, c = idx & 7;
      kt[idx] = qkv[(size_t)(kb + r) * 192 + 64 + h * HDIM + c];
    }
    __syncthreads();
    const float* kr = kt + half * 128 * 8;
#pragma unroll 4
    for (int j = 0; j < 128; ++j) {
      const float* k8 = kr + j * 8;
      float s = q[0]*k8[0] + q[1]*k8[1] + q[2]*k8[2] + q[3]*k8[3]
              + q[4]*k8[4] + q[5]*k8[5] + q[6]*k8[6] + q[7]*k8[7];
      mmax = fmaxf(mmax, s);
    }
  }
  mmax = fmaxf(mmax, __shfl_xor(mmax, 32, 64));

  // phase 2: exp-sum + PV
  float l = 0.f;
  float o[8] = {0.f, 0.f, 0.f, 0.f, 0.f, 0.f, 0.f, 0.f};
  for (int kb = 0; kb < MT; kb += 256) {
    __syncthreads();
    for (int idx = tid; idx < 2048; idx += 64) {
      int r = idx >> 3, c = idx & 7;
      kt[idx] = qkv[(size_t)(kb + r) * 192 + 64  + h * HDIM + c];
      vt[idx] = qkv[(size_t)(kb + r) * 192 + 128 + h * HDIM + c];
    }
    __syncthreads();
    const float* kr = kt + half * 128 * 8;
    const float* vr = vt + half * 128 * 8;
#pragma unroll 2
    for (int j = 0; j < 128; ++j) {
      const float* k8 = kr + j * 8;
      float s = q[0]*k8[0] + q[1]*k8[1] + q[2]*k8[2] + q[3]*k8[3]
              + q[4]*k8[4] + q[5]*k8[5] + q[6]*k8[6] + q[7]*k8[7];
      float p = __expf(s - mmax);
      l += p;
      const float* v8 = vr + j * 8;
#pragma unroll
      for (int c2 = 0; c2 < 8; ++c2) o[c2] += p * v8[c2];
    }
  }
  l += __shfl_xor(l, 32, 64);
#pragma unroll
  for (int c2 = 0; c2 < 8; ++c2) o[c2] += __shfl_xor(o[c2], 32, 64);

  if (half == 0) {
    float inv = 1.0f / l;
    float* op = o_out + (size_t)tok * DM + h * HDIM;
#pragma unroll
    for (int c2 = 0; c2 < 8; ++c2) op[c2] = o[c2] * inv;
  }
}

// ---------------------------------------------------------------- o-proj + residual + LN1
// one wave per token
__global__ __launch_bounds__(64) void oproj_ln_kernel(const float* __restrict__ o_in,
                                                      float* __restrict__ x,
                                                      const float* __restrict__ W,
                                                      const float* __restrict__ B,
                                                      const float* __restrict__ g,
                                                      const float* __restrict__ b) {
  const int t = blockIdx.x;
  const int d = threadIdx.x;
  __shared__ float orow[DM];
  orow[d] = o_in[(size_t)t * DM + d];
  __syncthreads();
  const float* w = W + (size_t)d * DM;
  float acc = B[d];
#pragma unroll
  for (int k = 0; k < DM; ++k) acc += orow[k] * w[k];
  float hv = x[(size_t)t * DM + d] + acc;
  float mu = wave_sum64(hv) * (1.0f / DM);
  float dv = hv - mu;
  float var = wave_sum64(dv * dv) * (1.0f / DM);
  x[(size_t)t * DM + d] = dv * rsqrtf(var + LN_EPS) * g[d] + b[d];
}

// ---------------------------------------------------------------- ff1 = relu(x @ W^T + b)
// one block per token, 256 threads
__global__ void ff1_kernel(const float* __restrict__ x, const float* __restrict__ W,
                           const float* __restrict__ B, float* __restrict__ ff) {
  const int t = blockIdx.x;
  const int o = threadIdx.x;
  __shared__ float xr[DM];
  if (o < DM) xr[o] = x[(size_t)t * DM + o];
  __syncthreads();
  const float* w = W + (size_t)o * DM;
  float acc = B[o];
#pragma unroll
  for (int k = 0; k < DM; ++k) acc += xr[k] * w[k];
  ff[(size_t)t * DFF + o] = fmaxf(acc, 0.0f);
}

// ---------------------------------------------------------------- ff2 + residual + LN2
__global__ __launch_bounds__(64) void ff2_ln_kernel(const float* __restrict__ ff,
                                                    float* __restrict__ x,
                                                    const float* __restrict__ W,
                                                    const float* __restrict__ B,
                                                    const float* __restrict__ g,
                                                    const float* __restrict__ b) {
  const int t = blockIdx.x;
  const int d = threadIdx.x;
  __shared__ float fr[DFF];
  for (int k = d; k < DFF; k += 64) fr[k] = ff[(size_t)t * DFF + k];
  __syncthreads();
  const float* w = W + (size_t)d * DFF;
  float acc = B[d];
#pragma unroll 8
  for (int k = 0; k < DFF; ++k) acc += fr[k] * w[k];
  float hv = x[(size_t)t * DM + d] + acc;
  float mu = wave_sum64(hv) * (1.0f / DM);
  float dv = hv - mu;
  float var = wave_sum64(dv * dv) * (1.0f / DM);
  x[(size_t)t * DM + d] = dv * rsqrtf(var + LN_EPS) * g[d] + b[d];
}

// ---------------------------------------------------------------- prune -> d_out
__global__ void prune_kernel(const float* __restrict__ x, const float* __restrict__ mask,
                             float* __restrict__ out) {
  int i = blockIdx.x * blockDim.x + threadIdx.x;
  if (i < MT * DM) out[i] = x[i] * mask[i & (DM - 1)];
}

// ---------------------------------------------------------------- row norms (x-pruned, rgb)
__global__ __launch_bounds__(64) void norms_kernel(const float* __restrict__ xm,
                                                   const float* __restrict__ rgb,
                                                   float* __restrict__ nrm) {
  const int row = blockIdx.x;
  const int d = threadIdx.x;
  const float* src = (row < MT) ? (xm + (size_t)row * DM) : (rgb + (size_t)(row - MT) * DM);
  float v = src[d];
  float s = wave_sum64(v * v);
  if (d == 0) nrm[row] = s;
}

// ---------------------------------------------------------------- MMD tile kernel
// grid (64, 64, 3); block 256; p=0:(x,x) p=1:(y,y) p=2:(x,y)
__global__ __launch_bounds__(256) void mmd_kernel(const float* __restrict__ xm,
                                                  const float* __restrict__ rgb,
                                                  const float* __restrict__ nrm,
                                                  float* __restrict__ acc) {
  const int p = blockIdx.z;
  const float* A = (p == 1) ? rgb : xm;
  const float* B = (p == 0) ? xm : rgb;
  const float* nA = (p == 1) ? (nrm + MT) : nrm;
  const float* nB = (p == 0) ? nrm : (nrm + MT);
  const int i0 = blockIdx.x * 64;
  const int j0 = blockIdx.y * 64;
  const int tid = threadIdx.x;

  __shared__ float At[64 * 65];
  __shared__ float Bt[64 * 65];
  for (int idx = tid; idx < 4096; idx += 256) {
    int r = idx >> 6, c = idx & 63;
    At[r * 65 + c] = A[(size_t)(i0 + r) * DM + c];
    Bt[r * 65 + c] = B[(size_t)(j0 + r) * DM + c];
  }
  __syncthreads();

  float local = 0.f;
  for (int pi = tid; pi < 4096; pi += 256) {
    int ii = pi >> 6, jj = pi & 63;
    const float* ar = At + ii * 65;
    const float* br = Bt + jj * 65;
    float dot = 0.f;
#pragma unroll
    for (int k = 0; k < DM; ++k) dot += ar[k] * br[k];
    float dist = nA[i0 + ii] + nB[j0 + jj] - 2.0f * dot;
    local += __expf(-0.5f * dist);
  }

  float tot = wave_sum64(local);
  __shared__ float wpart[4];
  if ((tid & 63) == 0) wpart[tid >> 6] = tot;
  __syncthreads();
  if (tid == 0) {
    atomicAdd(&acc[p], wpart[0] + wpart[1] + wpart[2] + wpart[3]);
  }
}

// ---------------------------------------------------------------- finalize scalar
__global__ void finalize_kernel(const float* __restrict__ acc, float* __restrict__ out) {
  if (threadIdx.x == 0 && blockIdx.x == 0) {
    const float invn = 1.0f / ((float)MT * (float)MT);
    out[0] = (acc[0] + acc[1] - 2.0f * acc[2]) * invn;
  }
}

// ================================================================ launcher
extern "C" void kernel_launch(void* const* d_in, const int* in_sizes, int n_in,
                              void* d_out, int out_size, void* d_ws, size_t ws_size,
                              hipStream_t stream) {
  const float* hsi  = (const float*)d_in[0];
  const float* rgb  = (const float*)d_in[1];
  const float* inw  = (const float*)d_in[2];
  const float* inb  = (const float*)d_in[3];
  const float* ow   = (const float*)d_in[4];
  const float* obv  = (const float*)d_in[5];
  const float* l1w  = (const float*)d_in[6];
  const float* l1b  = (const float*)d_in[7];
  const float* l2w  = (const float*)d_in[8];
  const float* l2b  = (const float*)d_in[9];
  const float* n1w  = (const float*)d_in[10];
  const float* n1b  = (const float*)d_in[11];
  const float* n2w  = (const float*)d_in[12];
  const float* n2b  = (const float*)d_in[13];
  const float* mask = (const float*)d_in[14];
  float* out = (float*)d_out;

  float* ws   = (float*)d_ws;
  float* x    = ws;                    // 4096*64   = 262144
  float* qkv  = ws + 262144;           // 4096*192  = 786432
  float* ao   = ws + 1048576;          // 4096*64   = 262144
  float* ffb  = ws + 1310720;          // 4096*256  = 1048576
  float* nrm  = ws + 2359296;          // 8192
  float* accp = ws + 2367488;          // 3

  hipMemsetAsync(accp, 0, 3 * sizeof(float), stream);

  copy_kernel<<<256, 256, 0, stream>>>((const float4*)hsi, (float4*)x, MT * DM / 4);

  for (int i = 0; i < NLAYER; ++i) {
    qkv_kernel<<<MT, 192, 0, stream>>>(x, inw + (size_t)i * 192 * DM, inb + (size_t)i * 192, qkv);
    attn_kernel<<<dim3(MT / 32, NHEAD), 64, 0, stream>>>(qkv, ao);
    oproj_ln_kernel<<<MT, 64, 0, stream>>>(ao, x, ow + (size_t)i * DM * DM, obv + (size_t)i * DM,
                                           n1w + (size_t)i * DM, n1b + (size_t)i * DM);
    ff1_kernel<<<MT, DFF, 0, stream>>>(x, l1w + (size_t)i * DFF * DM, l1b + (size_t)i * DFF, ffb);
    ff2_ln_kernel<<<MT, 64, 0, stream>>>(ffb, x, l2w + (size_t)i * DM * DFF, l2b + (size_t)i * DM,
                                         n2w + (size_t)i * DM, n2b + (size_t)i * DM);
  }

  prune_kernel<<<(MT * DM + 255) / 256, 256, 0, stream>>>(x, mask, out);
  norms_kernel<<<2 * MT, 64, 0, stream>>>(out, rgb, nrm);
  mmd_kernel<<<dim3(64, 64, 3), 256, 0, stream>>>(out, rgb, nrm, accp);
  finalize_kernel<<<1, 64, 0, stream>>>(accp, out + (size_t)MT * DM);
}

// Round 2
// 1614.937 us; speedup vs baseline: 1.4097x; 1.4097x over previous
//
#include <hip/hip_runtime.h>

#define MT 4096      // tokens = N*H*W = 4*32*32
#define DM 64        // d_model
#define NHEAD 8
#define HDIM 8
#define DFF 256
#define NLAYER 4
#define LN_EPS 1e-5f

__device__ __forceinline__ float wave_sum64(float v) {
#pragma unroll
  for (int m = 1; m < 64; m <<= 1) v += __shfl_xor(v, m, 64);
  return v;
}

// ---------------------------------------------------------------- copy x <- hsi
__global__ void copy_kernel(const float4* __restrict__ in, float4* __restrict__ out, int n4) {
  int i = blockIdx.x * blockDim.x + threadIdx.x;
  if (i < n4) out[i] = in[i];
}

// ---------------------------------------------------------------- qkv = x @ W^T + b
// one block per token, 192 threads (one per output feature)
__global__ void qkv_kernel(const float* __restrict__ x, const float* __restrict__ W,
                           const float* __restrict__ B, float* __restrict__ qkv) {
  const int t = blockIdx.x;
  const int o = threadIdx.x;
  __shared__ float xr[DM];
  if (o < DM) xr[o] = x[(size_t)t * DM + o];
  __syncthreads();
  const float* w = W + (size_t)o * DM;
  float acc = B[o];
#pragma unroll
  for (int k = 0; k < DM; ++k) acc += xr[k] * w[k];
  qkv[(size_t)t * 192 + o] = acc;
}

// ---------------------------------------------------------------- attention
// Single-pass online softmax. grid (MT/32, NHEAD), block 256.
// thread t: query = qb + (t&31), key-split = t>>5 (8 splits x 512 keys).
// Half-wave lanes share each key row -> broadcast loads from L2 (qkv ~3MB).
// Partials (m,l,o[8]) combined across splits via LDS (stride-10, conflict-free).
__global__ __launch_bounds__(256) void attn_kernel(const float* __restrict__ qkv,
                                                   float* __restrict__ o_out) {
  const int h = blockIdx.y;
  const int qb = blockIdx.x * 32;
  const int tid = threadIdx.x;
  const int ql = tid & 31;
  const int sp = tid >> 5;
  const int tok = qb + ql;

  float q0[8];
  const float* qp = qkv + (size_t)tok * 192 + h * HDIM;
#pragma unroll
  for (int j = 0; j < 8; ++j) q0[j] = qp[j] * 0.35355339059327373f;  // 1/sqrt(8)

  const float* kp = qkv + 64  + h * HDIM + (size_t)(sp * 512) * 192;
  const float* vp = qkv + 128 + h * HDIM + (size_t)(sp * 512) * 192;

  float m = -1e30f, l = 0.f;
  float o[8] = {0.f, 0.f, 0.f, 0.f, 0.f, 0.f, 0.f, 0.f};

  for (int kb = 0; kb < 512; kb += 8) {
    float s[8];
#pragma unroll
    for (int j = 0; j < 8; ++j) {
      const float* kr = kp + (size_t)j * 192;
      float4 ka = *(const float4*)kr;
      float4 kc = *(const float4*)(kr + 4);
      s[j] = q0[0]*ka.x + q0[1]*ka.y + q0[2]*ka.z + q0[3]*ka.w
           + q0[4]*kc.x + q0[5]*kc.y + q0[6]*kc.z + q0[7]*kc.w;
    }
    float cm = s[0];
#pragma unroll
    for (int j = 1; j < 8; ++j) cm = fmaxf(cm, s[j]);
    float mn = fmaxf(m, cm);
    float f = __expf(m - mn);
    m = mn;
    l *= f;
#pragma unroll
    for (int c = 0; c < 8; ++c) o[c] *= f;
#pragma unroll
    for (int j = 0; j < 8; ++j) {
      float p = __expf(s[j] - m);
      l += p;
      const float* vr = vp + (size_t)j * 192;
      float4 va = *(const float4*)vr;
      float4 vb = *(const float4*)(vr + 4);
      o[0] += p*va.x; o[1] += p*va.y; o[2] += p*va.z; o[3] += p*va.w;
      o[4] += p*vb.x; o[5] += p*vb.y; o[6] += p*vb.z; o[7] += p*vb.w;
    }
    kp += 8 * 192;
    vp += 8 * 192;
  }

  // combine 8 splits per query via LDS; [sp][ql] layout, stride 10 (no pow2 conflict)
  __shared__ float red[8][32][10];
  float* r = red[sp][ql];
  r[0] = m; r[1] = l;
#pragma unroll
  for (int c = 0; c < 8; ++c) r[2 + c] = o[c];
  __syncthreads();

  if (tid < 32) {
    float M = -1e30f;
#pragma unroll
    for (int s2 = 0; s2 < 8; ++s2) M = fmaxf(M, red[s2][tid][0]);
    float L = 0.f;
    float O[8] = {0.f, 0.f, 0.f, 0.f, 0.f, 0.f, 0.f, 0.f};
#pragma unroll
    for (int s2 = 0; s2 < 8; ++s2) {
      const float* rr = red[s2][tid];
      float w = __expf(rr[0] - M);
      L += rr[1] * w;
#pragma unroll
      for (int c = 0; c < 8; ++c) O[c] += rr[2 + c] * w;
    }
    float inv = 1.0f / L;
    float* op = o_out + (size_t)(qb + tid) * DM + h * HDIM;
#pragma unroll
    for (int c = 0; c < 8; ++c) op[c] = O[c] * inv;
  }
}

// ---------------------------------------------------------------- o-proj + residual + LN1
// one wave per token
__global__ __launch_bounds__(64) void oproj_ln_kernel(const float* __restrict__ o_in,
                                                      float* __restrict__ x,
                                                      const float* __restrict__ W,
                                                      const float* __restrict__ B,
                                                      const float* __restrict__ g,
                                                      const float* __restrict__ b) {
  const int t = blockIdx.x;
  const int d = threadIdx.x;
  __shared__ float orow[DM];
  orow[d] = o_in[(size_t)t * DM + d];
  __syncthreads();
  const float* w = W + (size_t)d * DM;
  float acc = B[d];
#pragma unroll
  for (int k = 0; k < DM; ++k) acc += orow[k] * w[k];
  float hv = x[(size_t)t * DM + d] + acc;
  float mu = wave_sum64(hv) * (1.0f / DM);
  float dv = hv - mu;
  float var = wave_sum64(dv * dv) * (1.0f / DM);
  x[(size_t)t * DM + d] = dv * rsqrtf(var + LN_EPS) * g[d] + b[d];
}

// ---------------------------------------------------------------- ff1 = relu(x @ W^T + b)
// one block per token, 256 threads
__global__ void ff1_kernel(const float* __restrict__ x, const float* __restrict__ W,
                           const float* __restrict__ B, float* __restrict__ ff) {
  const int t = blockIdx.x;
  const int o = threadIdx.x;
  __shared__ float xr[DM];
  if (o < DM) xr[o] = x[(size_t)t * DM + o];
  __syncthreads();
  const float* w = W + (size_t)o * DM;
  float acc = B[o];
#pragma unroll
  for (int k = 0; k < DM; ++k) acc += xr[k] * w[k];
  ff[(size_t)t * DFF + o] = fmaxf(acc, 0.0f);
}

// ---------------------------------------------------------------- ff2 + residual + LN2
__global__ __launch_bounds__(64) void ff2_ln_kernel(const float* __restrict__ ff,
                                                    float* __restrict__ x,
                                                    const float* __restrict__ W,
                                                    const float* __restrict__ B,
                                                    const float* __restrict__ g,
                                                    const float* __restrict__ b) {
  const int t = blockIdx.x;
  const int d = threadIdx.x;
  __shared__ float fr[DFF];
  for (int k = d; k < DFF; k += 64) fr[k] = ff[(size_t)t * DFF + k];
  __syncthreads();
  const float* w = W + (size_t)d * DFF;
  float acc = B[d];
#pragma unroll 8
  for (int k = 0; k < DFF; ++k) acc += fr[k] * w[k];
  float hv = x[(size_t)t * DM + d] + acc;
  float mu = wave_sum64(hv) * (1.0f / DM);
  float dv = hv - mu;
  float var = wave_sum64(dv * dv) * (1.0f / DM);
  x[(size_t)t * DM + d] = dv * rsqrtf(var + LN_EPS) * g[d] + b[d];
}

// ---------------------------------------------------------------- prune -> d_out
__global__ void prune_kernel(const float* __restrict__ x, const float* __restrict__ mask,
                             float* __restrict__ out) {
  int i = blockIdx.x * blockDim.x + threadIdx.x;
  if (i < MT * DM) out[i] = x[i] * mask[i & (DM - 1)];
}

// ---------------------------------------------------------------- row norms (x-pruned, rgb)
__global__ __launch_bounds__(64) void norms_kernel(const float* __restrict__ xm,
                                                   const float* __restrict__ rgb,
                                                   float* __restrict__ nrm) {
  const int row = blockIdx.x;
  const int d = threadIdx.x;
  const float* src = (row < MT) ? (xm + (size_t)row * DM) : (rgb + (size_t)(row - MT) * DM);
  float v = src[d];
  float s = wave_sum64(v * v);
  if (d == 0) nrm[row] = s;
}

// ---------------------------------------------------------------- MMD tile kernel
// grid (64, 64, 3); block 256; p=0:(x,x) p=1:(y,y) p=2:(x,y)
__global__ __launch_bounds__(256) void mmd_kernel(const float* __restrict__ xm,
                                                  const float* __restrict__ rgb,
                                                  const float* __restrict__ nrm,
                                                  float* __restrict__ acc) {
  const int p = blockIdx.z;
  const float* A = (p == 1) ? rgb : xm;
  const float* B = (p == 0) ? xm : rgb;
  const float* nA = (p == 1) ? (nrm + MT) : nrm;
  const float* nB = (p == 0) ? nrm : (nrm + MT);
  const int i0 = blockIdx.x * 64;
  const int j0 = blockIdx.y * 64;
  const int tid = threadIdx.x;

  __shared__ float At[64 * 65];
  __shared__ float Bt[64 * 65];
  for (int idx = tid; idx < 4096; idx += 256) {
    int r = idx >> 6, c = idx & 63;
    At[r * 65 + c] = A[(size_t)(i0 + r) * DM + c];
    Bt[r * 65 + c] = B[(size_t)(j0 + r) * DM + c];
  }
  __syncthreads();

  float local = 0.f;
  for (int pi = tid; pi < 4096; pi += 256) {
    int ii = pi >> 6, jj = pi & 63;
    const float* ar = At + ii * 65;
    const float* br = Bt + jj * 65;
    float dot = 0.f;
#pragma unroll
    for (int k = 0; k < DM; ++k) dot += ar[k] * br[k];
    float dist = nA[i0 + ii] + nB[j0 + jj] - 2.0f * dot;
    local += __expf(-0.5f * dist);
  }

  float tot = wave_sum64(local);
  __shared__ float wpart[4];
  if ((tid & 63) == 0) wpart[tid >> 6] = tot;
  __syncthreads();
  if (tid == 0) {
    atomicAdd(&acc[p], wpart[0] + wpart[1] + wpart[2] + wpart[3]);
  }
}

// ---------------------------------------------------------------- finalize scalar
__global__ void finalize_kernel(const float* __restrict__ acc, float* __restrict__ out) {
  if (threadIdx.x == 0 && blockIdx.x == 0) {
    const float invn = 1.0f / ((float)MT * (float)MT);
    out[0] = (acc[0] + acc[1] - 2.0f * acc[2]) * invn;
  }
}

// ================================================================ launcher
extern "C" void kernel_launch(void* const* d_in, const int* in_sizes, int n_in,
                              void* d_out, int out_size, void* d_ws, size_t ws_size,
                              hipStream_t stream) {
  const float* hsi  = (const float*)d_in[0];
  const float* rgb  = (const float*)d_in[1];
  const float* inw  = (const float*)d_in[2];
  const float* inb  = (const float*)d_in[3];
  const float* ow   = (const float*)d_in[4];
  const float* obv  = (const float*)d_in[5];
  const float* l1w  = (const float*)d_in[6];
  const float* l1b  = (const float*)d_in[7];
  const float* l2w  = (const float*)d_in[8];
  const float* l2b  = (const float*)d_in[9];
  const float* n1w  = (const float*)d_in[10];
  const float* n1b  = (const float*)d_in[11];
  const float* n2w  = (const float*)d_in[12];
  const float* n2b  = (const float*)d_in[13];
  const float* mask = (const float*)d_in[14];
  float* out = (float*)d_out;

  float* ws   = (float*)d_ws;
  float* x    = ws;                    // 4096*64   = 262144
  float* qkv  = ws + 262144;           // 4096*192  = 786432
  float* ao   = ws + 1048576;          // 4096*64   = 262144
  float* ffb  = ws + 1310720;          // 4096*256  = 1048576
  float* nrm  = ws + 2359296;          // 8192
  float* accp = ws + 2367488;          // 3

  hipMemsetAsync(accp, 0, 3 * sizeof(float), stream);

  copy_kernel<<<256, 256, 0, stream>>>((const float4*)hsi, (float4*)x, MT * DM / 4);

  for (int i = 0; i < NLAYER; ++i) {
    qkv_kernel<<<MT, 192, 0, stream>>>(x, inw + (size_t)i * 192 * DM, inb + (size_t)i * 192, qkv);
    attn_kernel<<<dim3(MT / 32, NHEAD), 256, 0, stream>>>(qkv, ao);
    oproj_ln_kernel<<<MT, 64, 0, stream>>>(ao, x, ow + (size_t)i * DM * DM, obv + (size_t)i * DM,
                                           n1w + (size_t)i * DM, n1b + (size_t)i * DM);
    ff1_kernel<<<MT, DFF, 0, stream>>>(x, l1w + (size_t)i * DFF * DM, l1b + (size_t)i * DFF, ffb);
    ff2_ln_kernel<<<MT, 64, 0, stream>>>(ffb, x, l2w + (size_t)i * DM * DFF, l2b + (size_t)i * DM,
                                         n2w + (size_t)i * DM, n2b + (size_t)i * DM);
  }

  prune_kernel<<<(MT * DM + 255) / 256, 256, 0, stream>>>(x, mask, out);
  norms_kernel<<<2 * MT, 64, 0, stream>>>(out, rgb, nrm);
  mmd_kernel<<<dim3(64, 64, 3), 256, 0, stream>>>(out, rgb, nrm, accp);
  finalize_kernel<<<1, 64, 0, stream>>>(accp, out + (size_t)MT * DM);
}

// Round 3
// 1070.886 us; speedup vs baseline: 2.1258x; 1.5080x over previous
//
#include <hip/hip_runtime.h>

#define MT 4096      // tokens = N*H*W = 4*32*32
#define DM 64        // d_model
#define NHEAD 8
#define HDIM 8
#define DFF 256
#define NLAYER 4
#define LN_EPS 1e-5f

typedef __attribute__((ext_vector_type(8))) short bf16x8;
typedef __attribute__((ext_vector_type(4))) short bf16x4;
typedef __attribute__((ext_vector_type(4))) float f32x4;

__device__ __forceinline__ float wave_sum64(float v) {
#pragma unroll
  for (int m = 1; m < 64; m <<= 1) v += __shfl_xor(v, m, 64);
  return v;
}

__device__ __forceinline__ short f2bf(float x) {   // RNE float->bf16
  union { float f; unsigned u; } v; v.f = x;
  unsigned r = v.u + 0x7fffu + ((v.u >> 16) & 1u);
  return (short)(r >> 16);
}

// ---------------------------------------------------------------- copy x <- hsi
__global__ void copy_kernel(const float4* __restrict__ in, float4* __restrict__ out, int n4) {
  int i = blockIdx.x * blockDim.x + threadIdx.x;
  if (i < n4) out[i] = in[i];
}

// ---------------------------------------------------------------- qkv = x @ W^T + b
__global__ void qkv_kernel(const float* __restrict__ x, const float* __restrict__ W,
                           const float* __restrict__ B, float* __restrict__ qkv) {
  const int t = blockIdx.x;
  const int o = threadIdx.x;
  __shared__ float xr[DM];
  if (o < DM) xr[o] = x[(size_t)t * DM + o];
  __syncthreads();
  const float* w = W + (size_t)o * DM;
  float acc = B[o];
#pragma unroll
  for (int k = 0; k < DM; ++k) acc += xr[k] * w[k];
  qkv[(size_t)t * 192 + o] = acc;
}

// ---------------------------------------------------------------- MFMA flash attention
// grid (64, 8): block = 64 queries x 1 head, 4 waves x 16 queries.
// Per 64-key tile: S^T = K.Q^T (4 mfma, k=8 padded to 32); online softmax with
// per-lane column = query (2-shuffle row stats); P -> per-wave LDS (stride 72);
// O^T = V^T.P^T (2 mfma, k=64). bf16 inputs, fp32 accum.
__global__ __launch_bounds__(256) void attn_kernel(const float* __restrict__ qkv,
                                                   float* __restrict__ o_out) {
  const int h = blockIdx.y;
  const int qbase = blockIdx.x * 64;
  const int tid = threadIdx.x;
  const int wid = tid >> 6;
  const int lane = tid & 63;
  const int n = lane & 15;     // query-in-strip (B col) / A row index
  const int quad = lane >> 4;

  __shared__ short Klds[64 * 8];        // [key][ch]
  __shared__ short Vtlds[8 * 72];       // [ch][key], stride 72
  __shared__ short Qlds[64 * 8];        // [q][ch], pre-scaled
  __shared__ short Plds[4][16 * 72];    // per-wave [query][key], stride 72

  for (int e = tid; e < 512; e += 256) {
    int row = e >> 3, ch = e & 7;
    Qlds[e] = f2bf(qkv[(size_t)(qbase + row) * 192 + h * 8 + ch] * 0.35355339059327373f);
  }
  __syncthreads();

  const bf16x8 zero8 = {0, 0, 0, 0, 0, 0, 0, 0};
  bf16x8 qb = zero8;
  if (quad == 0) qb = *(const bf16x8*)&Qlds[(wid * 16 + n) * 8];

  float m_run = -1e30f, l_run = 0.f;
  f32x4 o_acc = {0.f, 0.f, 0.f, 0.f};

  for (int kt = 0; kt < 64; ++kt) {
    const int kb0 = kt * 64;
    __syncthreads();
    for (int e = tid; e < 512; e += 256) {
      int row = e >> 3, ch = e & 7;
      const float* src = qkv + (size_t)(kb0 + row) * 192 + h * 8;
      Klds[e] = f2bf(src[64 + ch]);
      Vtlds[ch * 72 + row] = f2bf(src[128 + ch]);
    }
    __syncthreads();

    // S^T strip: rows = keys (4 mtiles x (quad*4+r)), col = query n
    f32x4 s[4];
#pragma unroll
    for (int mt = 0; mt < 4; ++mt) {
      bf16x8 ka = zero8;
      if (quad == 0) ka = *(const bf16x8*)&Klds[(mt * 16 + n) * 8];
      f32x4 zf = {0.f, 0.f, 0.f, 0.f};
      s[mt] = __builtin_amdgcn_mfma_f32_16x16x32_bf16(ka, qb, zf, 0, 0, 0);
    }

    // per-query (per-lane-column) online softmax stats
    float tmax = -1e30f;
#pragma unroll
    for (int mt = 0; mt < 4; ++mt)
#pragma unroll
      for (int r = 0; r < 4; ++r) tmax = fmaxf(tmax, s[mt][r]);
    tmax = fmaxf(tmax, __shfl_xor(tmax, 16, 64));
    tmax = fmaxf(tmax, __shfl_xor(tmax, 32, 64));

    float mn = fmaxf(m_run, tmax);
    float f = __expf(m_run - mn);
    m_run = mn;
    l_run *= f;
#pragma unroll
    for (int r = 0; r < 4; ++r) o_acc[r] *= f;

    float tsum = 0.f;
    short* pw = &Plds[wid][n * 72 + quad * 4];
#pragma unroll
    for (int mt = 0; mt < 4; ++mt) {
      float p0 = __expf(s[mt][0] - mn), p1 = __expf(s[mt][1] - mn);
      float p2 = __expf(s[mt][2] - mn), p3 = __expf(s[mt][3] - mn);
      tsum += (p0 + p1) + (p2 + p3);
      bf16x4 pv = {f2bf(p0), f2bf(p1), f2bf(p2), f2bf(p3)};
      *(bf16x4*)(pw + mt * 16) = pv;
    }
    tsum += __shfl_xor(tsum, 16, 64);
    tsum += __shfl_xor(tsum, 32, 64);
    l_run += tsum;

    // O^T += V^T . P^T  (k = 64 keys, 2 chunks)
#pragma unroll
    for (int c = 0; c < 2; ++c) {
      bf16x8 va = zero8;
      if (n < 8) va = *(const bf16x8*)&Vtlds[n * 72 + c * 32 + quad * 8];
      bf16x8 pb = *(const bf16x8*)&Plds[wid][n * 72 + c * 32 + quad * 8];
      o_acc = __builtin_amdgcn_mfma_f32_16x16x32_bf16(va, pb, o_acc, 0, 0, 0);
    }
  }

  // O^T: col = query n, rows = ch quad*4+r (real ch < 8 -> quads 0,1)
  float inv = 1.0f / l_run;
  if (quad < 2) {
    float4 val = {o_acc[0] * inv, o_acc[1] * inv, o_acc[2] * inv, o_acc[3] * inv};
    *(float4*)&o_out[(size_t)(qbase + wid * 16 + n) * DM + h * 8 + quad * 4] = val;
  }
}

// ---------------------------------------------------------------- o-proj + residual + LN1
__global__ __launch_bounds__(64) void oproj_ln_kernel(const float* __restrict__ o_in,
                                                      float* __restrict__ x,
                                                      const float* __restrict__ W,
                                                      const float* __restrict__ B,
                                                      const float* __restrict__ g,
                                                      const float* __restrict__ b) {
  const int t = blockIdx.x;
  const int d = threadIdx.x;
  __shared__ float orow[DM];
  orow[d] = o_in[(size_t)t * DM + d];
  __syncthreads();
  const float* w = W + (size_t)d * DM;
  float acc = B[d];
#pragma unroll
  for (int k = 0; k < DM; ++k) acc += orow[k] * w[k];
  float hv = x[(size_t)t * DM + d] + acc;
  float mu = wave_sum64(hv) * (1.0f / DM);
  float dv = hv - mu;
  float var = wave_sum64(dv * dv) * (1.0f / DM);
  x[(size_t)t * DM + d] = dv * rsqrtf(var + LN_EPS) * g[d] + b[d];
}

// ---------------------------------------------------------------- ff1 = relu(x @ W^T + b)
__global__ void ff1_kernel(const float* __restrict__ x, const float* __restrict__ W,
                           const float* __restrict__ B, float* __restrict__ ff) {
  const int t = blockIdx.x;
  const int o = threadIdx.x;
  __shared__ float xr[DM];
  if (o < DM) xr[o] = x[(size_t)t * DM + o];
  __syncthreads();
  const float* w = W + (size_t)o * DM;
  float acc = B[o];
#pragma unroll
  for (int k = 0; k < DM; ++k) acc += xr[k] * w[k];
  ff[(size_t)t * DFF + o] = fmaxf(acc, 0.0f);
}

// ---------------------------------------------------------------- ff2 + residual + LN2
__global__ __launch_bounds__(64) void ff2_ln_kernel(const float* __restrict__ ff,
                                                    float* __restrict__ x,
                                                    const float* __restrict__ W,
                                                    const float* __restrict__ B,
                                                    const float* __restrict__ g,
                                                    const float* __restrict__ b) {
  const int t = blockIdx.x;
  const int d = threadIdx.x;
  __shared__ float fr[DFF];
  for (int k = d; k < DFF; k += 64) fr[k] = ff[(size_t)t * DFF + k];
  __syncthreads();
  const float* w = W + (size_t)d * DFF;
  float acc = B[d];
#pragma unroll 8
  for (int k = 0; k < DFF; ++k) acc += fr[k] * w[k];
  float hv = x[(size_t)t * DM + d] + acc;
  float mu = wave_sum64(hv) * (1.0f / DM);
  float dv = hv - mu;
  float var = wave_sum64(dv * dv) * (1.0f / DM);
  x[(size_t)t * DM + d] = dv * rsqrtf(var + LN_EPS) * g[d] + b[d];
}

// ---------------------------------------------------------------- prune -> d_out
__global__ void prune_kernel(const float* __restrict__ x, const float* __restrict__ mask,
                             float* __restrict__ out) {
  int i = blockIdx.x * blockDim.x + threadIdx.x;
  if (i < MT * DM) out[i] = x[i] * mask[i & (DM - 1)];
}

// ---------------------------------------------------------------- row norms
__global__ __launch_bounds__(64) void norms_kernel(const float* __restrict__ xm,
                                                   const float* __restrict__ rgb,
                                                   float* __restrict__ nrm) {
  const int row = blockIdx.x;
  const int d = threadIdx.x;
  const float* src = (row < MT) ? (xm + (size_t)row * DM) : (rgb + (size_t)(row - MT) * DM);
  float v = src[d];
  float s = wave_sum64(v * v);
  if (d == 0) nrm[row] = s;
}

// ---------------------------------------------------------------- MMD tile kernel
__global__ __launch_bounds__(256) void mmd_kernel(const float* __restrict__ xm,
                                                  const float* __restrict__ rgb,
                                                  const float* __restrict__ nrm,
                                                  float* __restrict__ acc) {
  const int p = blockIdx.z;
  const float* A = (p == 1) ? rgb : xm;
  const float* B = (p == 0) ? xm : rgb;
  const float* nA = (p == 1) ? (nrm + MT) : nrm;
  const float* nB = (p == 0) ? nrm : (nrm + MT);
  const int i0 = blockIdx.x * 64;
  const int j0 = blockIdx.y * 64;
  const int tid = threadIdx.x;

  __shared__ float At[64 * 65];
  __shared__ float Bt[64 * 65];
  for (int idx = tid; idx < 4096; idx += 256) {
    int r = idx >> 6, c = idx & 63;
    At[r * 65 + c] = A[(size_t)(i0 + r) * DM + c];
    Bt[r * 65 + c] = B[(size_t)(j0 + r) * DM + c];
  }
  __syncthreads();

  float local = 0.f;
  for (int pi = tid; pi < 4096; pi += 256) {
    int ii = pi >> 6, jj = pi & 63;
    const float* ar = At + ii * 65;
    const float* br = Bt + jj * 65;
    float dot = 0.f;
#pragma unroll
    for (int k = 0; k < DM; ++k) dot += ar[k] * br[k];
    float dist = nA[i0 + ii] + nB[j0 + jj] - 2.0f * dot;
    local += __expf(-0.5f * dist);
  }

  float tot = wave_sum64(local);
  __shared__ float wpart[4];
  if ((tid & 63) == 0) wpart[tid >> 6] = tot;
  __syncthreads();
  if (tid == 0) {
    atomicAdd(&acc[p], wpart[0] + wpart[1] + wpart[2] + wpart[3]);
  }
}

// ---------------------------------------------------------------- finalize scalar
__global__ void finalize_kernel(const float* __restrict__ acc, float* __restrict__ out) {
  if (threadIdx.x == 0 && blockIdx.x == 0) {
    const float invn = 1.0f / ((float)MT * (float)MT);
    out[0] = (acc[0] + acc[1] - 2.0f * acc[2]) * invn;
  }
}

// ================================================================ launcher
extern "C" void kernel_launch(void* const* d_in, const int* in_sizes, int n_in,
                              void* d_out, int out_size, void* d_ws, size_t ws_size,
                              hipStream_t stream) {
  const float* hsi  = (const float*)d_in[0];
  const float* rgb  = (const float*)d_in[1];
  const float* inw  = (const float*)d_in[2];
  const float* inb  = (const float*)d_in[3];
  const float* ow   = (const float*)d_in[4];
  const float* obv  = (const float*)d_in[5];
  const float* l1w  = (const float*)d_in[6];
  const float* l1b  = (const float*)d_in[7];
  const float* l2w  = (const float*)d_in[8];
  const float* l2b  = (const float*)d_in[9];
  const float* n1w  = (const float*)d_in[10];
  const float* n1b  = (const float*)d_in[11];
  const float* n2w  = (const float*)d_in[12];
  const float* n2b  = (const float*)d_in[13];
  const float* mask = (const float*)d_in[14];
  float* out = (float*)d_out;

  float* ws   = (float*)d_ws;
  float* x    = ws;                    // 4096*64
  float* qkv  = ws + 262144;           // 4096*192
  float* ao   = ws + 1048576;          // 4096*64
  float* ffb  = ws + 1310720;          // 4096*256
  float* nrm  = ws + 2359296;          // 8192
  float* accp = ws + 2367488;          // 3

  hipMemsetAsync(accp, 0, 3 * sizeof(float), stream);

  copy_kernel<<<256, 256, 0, stream>>>((const float4*)hsi, (float4*)x, MT * DM / 4);

  for (int i = 0; i < NLAYER; ++i) {
    qkv_kernel<<<MT, 192, 0, stream>>>(x, inw + (size_t)i * 192 * DM, inb + (size_t)i * 192, qkv);
    attn_kernel<<<dim3(MT / 64, NHEAD), 256, 0, stream>>>(qkv, ao);
    oproj_ln_kernel<<<MT, 64, 0, stream>>>(ao, x, ow + (size_t)i * DM * DM, obv + (size_t)i * DM,
                                           n1w + (size_t)i * DM, n1b + (size_t)i * DM);
    ff1_kernel<<<MT, DFF, 0, stream>>>(x, l1w + (size_t)i * DFF * DM, l1b + (size_t)i * DFF, ffb);
    ff2_ln_kernel<<<MT, 64, 0, stream>>>(ffb, x, l2w + (size_t)i * DM * DFF, l2b + (size_t)i * DM,
                                         n2w + (size_t)i * DM, n2b + (size_t)i * DM);
  }

  prune_kernel<<<(MT * DM + 255) / 256, 256, 0, stream>>>(x, mask, out);
  norms_kernel<<<2 * MT, 64, 0, stream>>>(out, rgb, nrm);
  mmd_kernel<<<dim3(64, 64, 3), 256, 0, stream>>>(out, rgb, nrm, accp);
  finalize_kernel<<<1, 64, 0, stream>>>(accp, out + (size_t)MT * DM);
}

// Round 4
// 665.948 us; speedup vs baseline: 3.4185x; 1.6081x over previous
//
#include <hip/hip_runtime.h>

#define MT 4096      // tokens = N*H*W = 4*32*32
#define DM 64        // d_model
#define NHEAD 8
#define HDIM 8
#define DFF 256
#define NLAYER 4
#define LN_EPS 1e-5f

typedef __attribute__((ext_vector_type(8))) short bf16x8;
typedef __attribute__((ext_vector_type(4))) short bf16x4;
typedef __attribute__((ext_vector_type(4))) float f32x4;

__device__ __forceinline__ float wave_sum64(float v) {
#pragma unroll
  for (int m = 1; m < 64; m <<= 1) v += __shfl_xor(v, m, 64);
  return v;
}

__device__ __forceinline__ short f2bf(float x) {   // RNE float->bf16
  union { float f; unsigned u; } v; v.f = x;
  unsigned r = v.u + 0x7fffu + ((v.u >> 16) & 1u);
  return (short)(r >> 16);
}

// ---------------------------------------------------------------- copy x <- hsi
__global__ void copy_kernel(const float4* __restrict__ in, float4* __restrict__ out, int n4) {
  int i = blockIdx.x * blockDim.x + threadIdx.x;
  if (i < n4) out[i] = in[i];
}

// ---------------------------------------------------------------- weight transpose
// in: [L][R][C] -> out: [L][C][R]; R,C multiples of 32; 256 threads
__global__ void transpose_kernel(const float* __restrict__ in, float* __restrict__ out,
                                 int R, int C) {
  __shared__ float t[32][33];
  const float* ip = in + (size_t)blockIdx.z * R * C;
  float* op = out + (size_t)blockIdx.z * R * C;
  const int c0 = blockIdx.x * 32, r0 = blockIdx.y * 32;
  const int tx = threadIdx.x & 31, ty = threadIdx.x >> 5;
  for (int rr = ty; rr < 32; rr += 8)
    t[rr][tx] = ip[(size_t)(r0 + rr) * C + c0 + tx];
  __syncthreads();
  for (int cc = ty; cc < 32; cc += 8)
    op[(size_t)(c0 + cc) * R + r0 + tx] = t[tx][cc];
}

// ---------------------------------------------------------------- qkv = x @ W^T + b
// Wt: [64][192] k-major. Block = 4 tokens x 192 outputs.
__global__ __launch_bounds__(192) void qkv_kernel(const float* __restrict__ x,
                                                  const float* __restrict__ Wt,
                                                  const float* __restrict__ B,
                                                  float* __restrict__ qkv) {
  const int t0 = blockIdx.x * 4;
  const int o = threadIdx.x;
  __shared__ float xr[4][DM];
  for (int e = o; e < 64; e += 192)
    ((float4*)xr)[e] = ((const float4*)(x + (size_t)t0 * DM))[e];
  __syncthreads();
  float acc0 = B[o], acc1 = acc0, acc2 = acc0, acc3 = acc0;
#pragma unroll 8
  for (int k4 = 0; k4 < 16; ++k4) {
    float w0 = Wt[(k4 * 4 + 0) * 192 + o];
    float w1 = Wt[(k4 * 4 + 1) * 192 + o];
    float w2 = Wt[(k4 * 4 + 2) * 192 + o];
    float w3 = Wt[(k4 * 4 + 3) * 192 + o];
    float4 a = *(const float4*)&xr[0][k4 * 4];
    acc0 += a.x * w0 + a.y * w1 + a.z * w2 + a.w * w3;
    float4 b = *(const float4*)&xr[1][k4 * 4];
    acc1 += b.x * w0 + b.y * w1 + b.z * w2 + b.w * w3;
    float4 c = *(const float4*)&xr[2][k4 * 4];
    acc2 += c.x * w0 + c.y * w1 + c.z * w2 + c.w * w3;
    float4 d = *(const float4*)&xr[3][k4 * 4];
    acc3 += d.x * w0 + d.y * w1 + d.z * w2 + d.w * w3;
  }
  qkv[(size_t)(t0 + 0) * 192 + o] = acc0;
  qkv[(size_t)(t0 + 1) * 192 + o] = acc1;
  qkv[(size_t)(t0 + 2) * 192 + o] = acc2;
  qkv[(size_t)(t0 + 3) * 192 + o] = acc3;
}

// ---------------------------------------------------------------- MFMA flash attention
// grid (64, 8): block = 64 queries x 1 head, 4 waves x 16 queries.
// K-tile = 256 keys (16 staging iters). Per 64-key sub-tile: S^T = K.Q^T
// (4 mfma, k=8 padded to 32); online softmax; P via per-wave LDS;
// O^T = V^T.P^T (2 mfma).
__global__ __launch_bounds__(256) void attn_kernel(const float* __restrict__ qkv,
                                                   float* __restrict__ o_out) {
  const int h = blockIdx.y;
  const int qbase = blockIdx.x * 64;
  const int tid = threadIdx.x;
  const int wid = tid >> 6;
  const int lane = tid & 63;
  const int n = lane & 15;
  const int quad = lane >> 4;

  __shared__ short Klds[256 * 8];       // [key][ch]
  __shared__ short Vtlds[8 * 264];      // [ch][key], stride 264
  __shared__ short Qlds[64 * 8];        // [q][ch], pre-scaled
  __shared__ short Plds[4][16 * 72];    // per-wave [query][key64], stride 72

  for (int e = tid; e < 512; e += 256) {
    int row = e >> 3, ch = e & 7;
    Qlds[e] = f2bf(qkv[(size_t)(qbase + row) * 192 + h * 8 + ch] * 0.35355339059327373f);
  }
  __syncthreads();

  const bf16x8 zero8 = {0, 0, 0, 0, 0, 0, 0, 0};
  bf16x8 qb = zero8;
  if (quad == 0) qb = *(const bf16x8*)&Qlds[(wid * 16 + n) * 8];

  float m_run = -1e30f, l_run = 0.f;
  f32x4 o_acc = {0.f, 0.f, 0.f, 0.f};

  for (int kt = 0; kt < 16; ++kt) {
    __syncthreads();
    {
      const float* src = qkv + (size_t)(kt * 256 + tid) * 192 + h * 8;
      float4 k0 = *(const float4*)(src + 64);
      float4 k1 = *(const float4*)(src + 68);
      float4 v0 = *(const float4*)(src + 128);
      float4 v1 = *(const float4*)(src + 132);
      bf16x8 kr = {f2bf(k0.x), f2bf(k0.y), f2bf(k0.z), f2bf(k0.w),
                   f2bf(k1.x), f2bf(k1.y), f2bf(k1.z), f2bf(k1.w)};
      *(bf16x8*)&Klds[tid * 8] = kr;
      Vtlds[0 * 264 + tid] = f2bf(v0.x);
      Vtlds[1 * 264 + tid] = f2bf(v0.y);
      Vtlds[2 * 264 + tid] = f2bf(v0.z);
      Vtlds[3 * 264 + tid] = f2bf(v0.w);
      Vtlds[4 * 264 + tid] = f2bf(v1.x);
      Vtlds[5 * 264 + tid] = f2bf(v1.y);
      Vtlds[6 * 264 + tid] = f2bf(v1.z);
      Vtlds[7 * 264 + tid] = f2bf(v1.w);
    }
    __syncthreads();

#pragma unroll
    for (int sub = 0; sub < 4; ++sub) {
      const short* kbase = &Klds[sub * 64 * 8];
      f32x4 s[4];
#pragma unroll
      for (int mt = 0; mt < 4; ++mt) {
        bf16x8 ka = zero8;
        if (quad == 0) ka = *(const bf16x8*)&kbase[(mt * 16 + n) * 8];
        f32x4 zf = {0.f, 0.f, 0.f, 0.f};
        s[mt] = __builtin_amdgcn_mfma_f32_16x16x32_bf16(ka, qb, zf, 0, 0, 0);
      }

      float tmax = -1e30f;
#pragma unroll
      for (int mt = 0; mt < 4; ++mt)
#pragma unroll
        for (int r = 0; r < 4; ++r) tmax = fmaxf(tmax, s[mt][r]);
      tmax = fmaxf(tmax, __shfl_xor(tmax, 16, 64));
      tmax = fmaxf(tmax, __shfl_xor(tmax, 32, 64));

      float mn = fmaxf(m_run, tmax);
      float f = __expf(m_run - mn);
      m_run = mn;
      l_run *= f;
#pragma unroll
      for (int r = 0; r < 4; ++r) o_acc[r] *= f;

      float tsum = 0.f;
      short* pw = &Plds[wid][n * 72 + quad * 4];
#pragma unroll
      for (int mt = 0; mt < 4; ++mt) {
        float p0 = __expf(s[mt][0] - mn), p1 = __expf(s[mt][1] - mn);
        float p2 = __expf(s[mt][2] - mn), p3 = __expf(s[mt][3] - mn);
        tsum += (p0 + p1) + (p2 + p3);
        bf16x4 pv = {f2bf(p0), f2bf(p1), f2bf(p2), f2bf(p3)};
        *(bf16x4*)(pw + mt * 16) = pv;
      }
      tsum += __shfl_xor(tsum, 16, 64);
      tsum += __shfl_xor(tsum, 32, 64);
      l_run += tsum;

#pragma unroll
      for (int c = 0; c < 2; ++c) {
        bf16x8 va = zero8;
        if (n < 8) va = *(const bf16x8*)&Vtlds[n * 264 + sub * 64 + c * 32 + quad * 8];
        bf16x8 pb = *(const bf16x8*)&Plds[wid][n * 72 + c * 32 + quad * 8];
        o_acc = __builtin_amdgcn_mfma_f32_16x16x32_bf16(va, pb, o_acc, 0, 0, 0);
      }
    }
  }

  float inv = 1.0f / l_run;
  if (quad < 2) {
    float4 val = {o_acc[0] * inv, o_acc[1] * inv, o_acc[2] * inv, o_acc[3] * inv};
    *(float4*)&o_out[(size_t)(qbase + wid * 16 + n) * DM + h * 8 + quad * 4] = val;
  }
}

// ---------------------------------------------------------------- o-proj + residual + LN1
// Wt: [64][64] k-major. Block = 4 tokens x 64 (one wave).
__global__ __launch_bounds__(64) void oproj_ln_kernel(const float* __restrict__ o_in,
                                                      float* __restrict__ x,
                                                      const float* __restrict__ Wt,
                                                      const float* __restrict__ B,
                                                      const float* __restrict__ g,
                                                      const float* __restrict__ b) {
  const int t0 = blockIdx.x * 4;
  const int d = threadIdx.x;
  __shared__ float orow[4][DM];
  ((float4*)orow)[d] = ((const float4*)(o_in + (size_t)t0 * DM))[d];
  __syncthreads();
  float acc0 = B[d], acc1 = acc0, acc2 = acc0, acc3 = acc0;
#pragma unroll 8
  for (int k4 = 0; k4 < 16; ++k4) {
    float w0 = Wt[(k4 * 4 + 0) * 64 + d];
    float w1 = Wt[(k4 * 4 + 1) * 64 + d];
    float w2 = Wt[(k4 * 4 + 2) * 64 + d];
    float w3 = Wt[(k4 * 4 + 3) * 64 + d];
    float4 a = *(const float4*)&orow[0][k4 * 4];
    acc0 += a.x * w0 + a.y * w1 + a.z * w2 + a.w * w3;
    float4 bb = *(const float4*)&orow[1][k4 * 4];
    acc1 += bb.x * w0 + bb.y * w1 + bb.z * w2 + bb.w * w3;
    float4 c = *(const float4*)&orow[2][k4 * 4];
    acc2 += c.x * w0 + c.y * w1 + c.z * w2 + c.w * w3;
    float4 e = *(const float4*)&orow[3][k4 * 4];
    acc3 += e.x * w0 + e.y * w1 + e.z * w2 + e.w * w3;
  }
  float accs[4] = {acc0, acc1, acc2, acc3};
#pragma unroll
  for (int t = 0; t < 4; ++t) {
    float hv = x[(size_t)(t0 + t) * DM + d] + accs[t];
    float mu = wave_sum64(hv) * (1.0f / DM);
    float dv = hv - mu;
    float var = wave_sum64(dv * dv) * (1.0f / DM);
    x[(size_t)(t0 + t) * DM + d] = dv * rsqrtf(var + LN_EPS) * g[d] + b[d];
  }
}

// ---------------------------------------------------------------- ff1 = relu(x @ W^T + b)
// Wt: [64][256] k-major. Block = 4 tokens x 256 outputs.
__global__ __launch_bounds__(256) void ff1_kernel(const float* __restrict__ x,
                                                  const float* __restrict__ Wt,
                                                  const float* __restrict__ B,
                                                  float* __restrict__ ff) {
  const int t0 = blockIdx.x * 4;
  const int o = threadIdx.x;
  __shared__ float xr[4][DM];
  if (o < 64) ((float4*)xr)[o] = ((const float4*)(x + (size_t)t0 * DM))[o];
  __syncthreads();
  float acc0 = B[o], acc1 = acc0, acc2 = acc0, acc3 = acc0;
#pragma unroll 8
  for (int k4 = 0; k4 < 16; ++k4) {
    float w0 = Wt[(k4 * 4 + 0) * 256 + o];
    float w1 = Wt[(k4 * 4 + 1) * 256 + o];
    float w2 = Wt[(k4 * 4 + 2) * 256 + o];
    float w3 = Wt[(k4 * 4 + 3) * 256 + o];
    float4 a = *(const float4*)&xr[0][k4 * 4];
    acc0 += a.x * w0 + a.y * w1 + a.z * w2 + a.w * w3;
    float4 b = *(const float4*)&xr[1][k4 * 4];
    acc1 += b.x * w0 + b.y * w1 + b.z * w2 + b.w * w3;
    float4 c = *(const float4*)&xr[2][k4 * 4];
    acc2 += c.x * w0 + c.y * w1 + c.z * w2 + c.w * w3;
    float4 e = *(const float4*)&xr[3][k4 * 4];
    acc3 += e.x * w0 + e.y * w1 + e.z * w2 + e.w * w3;
  }
  ff[(size_t)(t0 + 0) * DFF + o] = fmaxf(acc0, 0.0f);
  ff[(size_t)(t0 + 1) * DFF + o] = fmaxf(acc1, 0.0f);
  ff[(size_t)(t0 + 2) * DFF + o] = fmaxf(acc2, 0.0f);
  ff[(size_t)(t0 + 3) * DFF + o] = fmaxf(acc3, 0.0f);
}

// ---------------------------------------------------------------- ff2 + residual + LN2
// Wt: [256][64] k-major. Block = 4 tokens x 64 (one wave).
__global__ __launch_bounds__(64) void ff2_ln_kernel(const float* __restrict__ ff,
                                                    float* __restrict__ x,
                                                    const float* __restrict__ Wt,
                                                    const float* __restrict__ B,
                                                    const float* __restrict__ g,
                                                    const float* __restrict__ b) {
  const int t0 = blockIdx.x * 4;
  const int d = threadIdx.x;
  __shared__ float fr[4][DFF];
  for (int e = d; e < 256; e += 64)
    ((float4*)fr)[e] = ((const float4*)(ff + (size_t)t0 * DFF))[e];
  __syncthreads();
  float acc0 = B[d], acc1 = acc0, acc2 = acc0, acc3 = acc0;
#pragma unroll 8
  for (int k4 = 0; k4 < 64; ++k4) {
    float w0 = Wt[(k4 * 4 + 0) * 64 + d];
    float w1 = Wt[(k4 * 4 + 1) * 64 + d];
    float w2 = Wt[(k4 * 4 + 2) * 64 + d];
    float w3 = Wt[(k4 * 4 + 3) * 64 + d];
    float4 a = *(const float4*)&fr[0][k4 * 4];
    acc0 += a.x * w0 + a.y * w1 + a.z * w2 + a.w * w3;
    float4 bb = *(const float4*)&fr[1][k4 * 4];
    acc1 += bb.x * w0 + bb.y * w1 + bb.z * w2 + bb.w * w3;
    float4 c = *(const float4*)&fr[2][k4 * 4];
    acc2 += c.x * w0 + c.y * w1 + c.z * w2 + c.w * w3;
    float4 e = *(const float4*)&fr[3][k4 * 4];
    acc3 += e.x * w0 + e.y * w1 + e.z * w2 + e.w * w3;
  }
  float accs[4] = {acc0, acc1, acc2, acc3};
#pragma unroll
  for (int t = 0; t < 4; ++t) {
    float hv = x[(size_t)(t0 + t) * DM + d] + accs[t];
    float mu = wave_sum64(hv) * (1.0f / DM);
    float dv = hv - mu;
    float var = wave_sum64(dv * dv) * (1.0f / DM);
    x[(size_t)(t0 + t) * DM + d] = dv * rsqrtf(var + LN_EPS) * g[d] + b[d];
  }
}

// ---------------------------------------------------------------- prune -> d_out
__global__ void prune_kernel(const float* __restrict__ x, const float* __restrict__ mask,
                             float* __restrict__ out) {
  int i = blockIdx.x * blockDim.x + threadIdx.x;
  if (i < MT * DM) out[i] = x[i] * mask[i & (DM - 1)];
}

// ---------------------------------------------------------------- row norms
__global__ __launch_bounds__(64) void norms_kernel(const float* __restrict__ xm,
                                                   const float* __restrict__ rgb,
                                                   float* __restrict__ nrm) {
  const int row = blockIdx.x;
  const int d = threadIdx.x;
  const float* src = (row < MT) ? (xm + (size_t)row * DM) : (rgb + (size_t)(row - MT) * DM);
  float v = src[d];
  float s = wave_sum64(v * v);
  if (d == 0) nrm[row] = s;
}

// ---------------------------------------------------------------- MMD via MFMA
// grid (64,64,3); block 256 (4 waves). 64x64 pair tile; A,B staged as bf16 in
// fragment-linear LDS ([strip][chunk] blocks of 16 rows x 8ch, stride 136 shorts).
// Wave w: output strip w (16 rows), iterates 4 n-tiles; 8 mfma total.
#define CHB 136
__global__ __launch_bounds__(256) void mmd_kernel(const float* __restrict__ xm,
                                                  const float* __restrict__ rgb,
                                                  const float* __restrict__ nrm,
                                                  float* __restrict__ acc) {
  const int p = blockIdx.z;
  const float* A = (p == 1) ? rgb : xm;
  const float* B = (p == 0) ? xm : rgb;
  const float* nA = (p == 1) ? (nrm + MT) : nrm;
  const float* nB = (p == 0) ? nrm : (nrm + MT);
  const int i0 = blockIdx.x * 64;
  const int j0 = blockIdx.y * 64;
  const int tid = threadIdx.x;
  const int wid = tid >> 6;
  const int lane = tid & 63;
  const int n = lane & 15;
  const int quad = lane >> 4;

  __shared__ short At[32 * CHB];
  __shared__ short Bt[32 * CHB];
  __shared__ float nAl[64], nBl[64];

  // stage: thread t -> row r = t>>2, k0 = (t&3)*16 (16 floats = 2 chunks)
  {
    const int r = tid >> 2, k0 = (tid & 3) * 16;
    const int s = r >> 4, rr = r & 15, ca = (tid & 3) * 2;
    const float* ap = A + (size_t)(i0 + r) * DM + k0;
    const float* bp = B + (size_t)(j0 + r) * DM + k0;
    float4 a0 = *(const float4*)(ap + 0), a1 = *(const float4*)(ap + 4);
    float4 a2 = *(const float4*)(ap + 8), a3 = *(const float4*)(ap + 12);
    bf16x8 av0 = {f2bf(a0.x), f2bf(a0.y), f2bf(a0.z), f2bf(a0.w),
                  f2bf(a1.x), f2bf(a1.y), f2bf(a1.z), f2bf(a1.w)};
    bf16x8 av1 = {f2bf(a2.x), f2bf(a2.y), f2bf(a2.z), f2bf(a2.w),
                  f2bf(a3.x), f2bf(a3.y), f2bf(a3.z), f2bf(a3.w)};
    *(bf16x8*)&At[(s * 8 + ca) * CHB + rr * 8] = av0;
    *(bf16x8*)&At[(s * 8 + ca + 1) * CHB + rr * 8] = av1;
    float4 b0 = *(const float4*)(bp + 0), b1 = *(const float4*)(bp + 4);
    float4 b2 = *(const float4*)(bp + 8), b3 = *(const float4*)(bp + 12);
    bf16x8 bv0 = {f2bf(b0.x), f2bf(b0.y), f2bf(b0.z), f2bf(b0.w),
                  f2bf(b1.x), f2bf(b1.y), f2bf(b1.z), f2bf(b1.w)};
    bf16x8 bv1 = {f2bf(b2.x), f2bf(b2.y), f2bf(b2.z), f2bf(b2.w),
                  f2bf(b3.x), f2bf(b3.y), f2bf(b3.z), f2bf(b3.w)};
    *(bf16x8*)&Bt[(s * 8 + ca) * CHB + rr * 8] = bv0;
    *(bf16x8*)&Bt[(s * 8 + ca + 1) * CHB + rr * 8] = bv1;
    if (tid < 64) nAl[tid] = nA[i0 + tid];
    else if (tid < 128) nBl[tid - 64] = nB[j0 + tid - 64];
  }
  __syncthreads();

  bf16x8 a0 = *(const bf16x8*)&At[(wid * 8 + quad) * CHB + n * 8];
  bf16x8 a1 = *(const bf16x8*)&At[(wid * 8 + 4 + quad) * CHB + n * 8];

  float local = 0.f;
#pragma unroll
  for (int nt = 0; nt < 4; ++nt) {
    bf16x8 b0 = *(const bf16x8*)&Bt[(nt * 8 + quad) * CHB + n * 8];
    bf16x8 b1 = *(const bf16x8*)&Bt[(nt * 8 + 4 + quad) * CHB + n * 8];
    f32x4 zf = {0.f, 0.f, 0.f, 0.f};
    f32x4 d4 = __builtin_amdgcn_mfma_f32_16x16x32_bf16(a0, b0, zf, 0, 0, 0);
    d4 = __builtin_amdgcn_mfma_f32_16x16x32_bf16(a1, b1, d4, 0, 0, 0);
    float nb = nBl[nt * 16 + n];
#pragma unroll
    for (int r = 0; r < 4; ++r) {
      float na = nAl[wid * 16 + quad * 4 + r];
      float dist = na + nb - 2.0f * d4[r];
      local += __expf(-0.5f * dist);
    }
  }

  float tot = wave_sum64(local);
  __shared__ float wpart[4];
  if (lane == 0) wpart[wid] = tot;
  __syncthreads();
  if (tid == 0) atomicAdd(&acc[p], wpart[0] + wpart[1] + wpart[2] + wpart[3]);
}

// ---------------------------------------------------------------- finalize scalar
__global__ void finalize_kernel(const float* __restrict__ acc, float* __restrict__ out) {
  if (threadIdx.x == 0 && blockIdx.x == 0) {
    const float invn = 1.0f / ((float)MT * (float)MT);
    out[0] = (acc[0] + acc[1] - 2.0f * acc[2]) * invn;
  }
}

// ================================================================ launcher
extern "C" void kernel_launch(void* const* d_in, const int* in_sizes, int n_in,
                              void* d_out, int out_size, void* d_ws, size_t ws_size,
                              hipStream_t stream) {
  const float* hsi  = (const float*)d_in[0];
  const float* rgb  = (const float*)d_in[1];
  const float* inw  = (const float*)d_in[2];
  const float* inb  = (const float*)d_in[3];
  const float* ow   = (const float*)d_in[4];
  const float* obv  = (const float*)d_in[5];
  const float* l1w  = (const float*)d_in[6];
  const float* l1b  = (const float*)d_in[7];
  const float* l2w  = (const float*)d_in[8];
  const float* l2b  = (const float*)d_in[9];
  const float* n1w  = (const float*)d_in[10];
  const float* n1b  = (const float*)d_in[11];
  const float* n2w  = (const float*)d_in[12];
  const float* n2b  = (const float*)d_in[13];
  const float* mask = (const float*)d_in[14];
  float* out = (float*)d_out;

  float* ws   = (float*)d_ws;
  float* x    = ws;                    // 4096*64
  float* qkv  = ws + 262144;           // 4096*192
  float* ao   = ws + 1048576;          // 4096*64
  float* ffb  = ws + 1310720;          // 4096*256
  float* nrm  = ws + 2359296;          // 8192
  float* accp = ws + 2367488;          // 3

  // transposed weights live in d_out (dead until prune_kernel)
  float* Wti = out;                    // 4*64*192 = 49152
  float* Wto = out + 49152;            // 4*64*64  = 16384
  float* Wt1 = out + 65536;            // 4*64*256 = 65536
  float* Wt2 = out + 131072;           // 4*256*64 = 65536  (total 196608 <= 262144)

  hipMemsetAsync(accp, 0, 3 * sizeof(float), stream);

  transpose_kernel<<<dim3(2, 6, 4), 256, 0, stream>>>(inw, Wti, 192, 64);
  transpose_kernel<<<dim3(2, 2, 4), 256, 0, stream>>>(ow,  Wto, 64, 64);
  transpose_kernel<<<dim3(2, 8, 4), 256, 0, stream>>>(l1w, Wt1, 256, 64);
  transpose_kernel<<<dim3(8, 2, 4), 256, 0, stream>>>(l2w, Wt2, 64, 256);

  copy_kernel<<<256, 256, 0, stream>>>((const float4*)hsi, (float4*)x, MT * DM / 4);

  for (int i = 0; i < NLAYER; ++i) {
    qkv_kernel<<<MT / 4, 192, 0, stream>>>(x, Wti + (size_t)i * 192 * DM, inb + (size_t)i * 192, qkv);
    attn_kernel<<<dim3(MT / 64, NHEAD), 256, 0, stream>>>(qkv, ao);
    oproj_ln_kernel<<<MT / 4, 64, 0, stream>>>(ao, x, Wto + (size_t)i * DM * DM, obv + (size_t)i * DM,
                                               n1w + (size_t)i * DM, n1b + (size_t)i * DM);
    ff1_kernel<<<MT / 4, 256, 0, stream>>>(x, Wt1 + (size_t)i * DFF * DM, l1b + (size_t)i * DFF, ffb);
    ff2_ln_kernel<<<MT / 4, 64, 0, stream>>>(ffb, x, Wt2 + (size_t)i * DM * DFF, l2b + (size_t)i * DM,
                                             n2w + (size_t)i * DM, n2b + (size_t)i * DM);
  }

  prune_kernel<<<(MT * DM + 255) / 256, 256, 0, stream>>>(x, mask, out);
  norms_kernel<<<2 * MT, 64, 0, stream>>>(out, rgb, nrm);
  mmd_kernel<<<dim3(64, 64, 3), 256, 0, stream>>>(out, rgb, nrm, accp);
  finalize_kernel<<<1, 64, 0, stream>>>(accp, out + (size_t)MT * DM);
}

// Round 5
// 566.910 us; speedup vs baseline: 4.0157x; 1.1747x over previous
//
#include <hip/hip_runtime.h>

#define MT 4096      // tokens = N*H*W = 4*32*32
#define DM 64        // d_model
#define NHEAD 8
#define HDIM 8
#define DFF 256
#define NLAYER 4
#define LN_EPS 1e-5f

typedef __attribute__((ext_vector_type(8))) short bf16x8;
typedef __attribute__((ext_vector_type(4))) short bf16x4;
typedef __attribute__((ext_vector_type(4))) float f32x4;

__device__ __forceinline__ float wave_sum64(float v) {
#pragma unroll
  for (int m = 1; m < 64; m <<= 1) v += __shfl_xor(v, m, 64);
  return v;
}

__device__ __forceinline__ short f2bf(float x) {   // RNE float->bf16
  union { float f; unsigned u; } v; v.f = x;
  unsigned r = v.u + 0x7fffu + ((v.u >> 16) & 1u);
  return (short)(r >> 16);
}

// ---------------------------------------------------------------- copy x <- hsi
__global__ void copy_kernel(const float4* __restrict__ in, float4* __restrict__ out, int n4) {
  int i = blockIdx.x * blockDim.x + threadIdx.x;
  if (i < n4) out[i] = in[i];
}

// ---------------------------------------------------------------- weight transpose
__global__ void transpose_kernel(const float* __restrict__ in, float* __restrict__ out,
                                 int R, int C) {
  __shared__ float t[32][33];
  const float* ip = in + (size_t)blockIdx.z * R * C;
  float* op = out + (size_t)blockIdx.z * R * C;
  const int c0 = blockIdx.x * 32, r0 = blockIdx.y * 32;
  const int tx = threadIdx.x & 31, ty = threadIdx.x >> 5;
  for (int rr = ty; rr < 32; rr += 8)
    t[rr][tx] = ip[(size_t)(r0 + rr) * C + c0 + tx];
  __syncthreads();
  for (int cc = ty; cc < 32; cc += 8)
    op[(size_t)(c0 + cc) * R + r0 + tx] = t[tx][cc];
}

// ---------------------------------------------------------------- qkv = x @ W^T + b
__global__ __launch_bounds__(192) void qkv_kernel(const float* __restrict__ x,
                                                  const float* __restrict__ Wt,
                                                  const float* __restrict__ B,
                                                  float* __restrict__ qkv) {
  const int t0 = blockIdx.x * 4;
  const int o = threadIdx.x;
  __shared__ float xr[4][DM];
  for (int e = o; e < 64; e += 192)
    ((float4*)xr)[e] = ((const float4*)(x + (size_t)t0 * DM))[e];
  __syncthreads();
  float acc0 = B[o], acc1 = acc0, acc2 = acc0, acc3 = acc0;
#pragma unroll 8
  for (int k4 = 0; k4 < 16; ++k4) {
    float w0 = Wt[(k4 * 4 + 0) * 192 + o];
    float w1 = Wt[(k4 * 4 + 1) * 192 + o];
    float w2 = Wt[(k4 * 4 + 2) * 192 + o];
    float w3 = Wt[(k4 * 4 + 3) * 192 + o];
    float4 a = *(const float4*)&xr[0][k4 * 4];
    acc0 += a.x * w0 + a.y * w1 + a.z * w2 + a.w * w3;
    float4 b = *(const float4*)&xr[1][k4 * 4];
    acc1 += b.x * w0 + b.y * w1 + b.z * w2 + b.w * w3;
    float4 c = *(const float4*)&xr[2][k4 * 4];
    acc2 += c.x * w0 + c.y * w1 + c.z * w2 + c.w * w3;
    float4 d = *(const float4*)&xr[3][k4 * 4];
    acc3 += d.x * w0 + d.y * w1 + d.z * w2 + d.w * w3;
  }
  qkv[(size_t)(t0 + 0) * 192 + o] = acc0;
  qkv[(size_t)(t0 + 1) * 192 + o] = acc1;
  qkv[(size_t)(t0 + 2) * 192 + o] = acc2;
  qkv[(size_t)(t0 + 3) * 192 + o] = acc3;
}

// ---------------------------------------------------------------- attn pre-pack
// qkv fp32 -> Qbf [h][t][8] (pre-scaled), Kbf [h][t][8], Vtb [h][ch][t]; bf16
__global__ __launch_bounds__(256) void attn_pack_kernel(const float* __restrict__ qkv,
                                                        short* __restrict__ Qbf,
                                                        short* __restrict__ Kbf,
                                                        short* __restrict__ Vtb) {
  const int t = blockIdx.x * 256 + threadIdx.x;
#pragma unroll
  for (int h = 0; h < NHEAD; ++h) {
    const float* src = qkv + (size_t)t * 192 + h * 8;
    float4 q0 = *(const float4*)(src + 0), q1 = *(const float4*)(src + 4);
    bf16x8 qv = {f2bf(q0.x * 0.35355339059327373f), f2bf(q0.y * 0.35355339059327373f),
                 f2bf(q0.z * 0.35355339059327373f), f2bf(q0.w * 0.35355339059327373f),
                 f2bf(q1.x * 0.35355339059327373f), f2bf(q1.y * 0.35355339059327373f),
                 f2bf(q1.z * 0.35355339059327373f), f2bf(q1.w * 0.35355339059327373f)};
    *(bf16x8*)&Qbf[((size_t)h * MT + t) * 8] = qv;
    float4 k0 = *(const float4*)(src + 64), k1 = *(const float4*)(src + 68);
    bf16x8 kv = {f2bf(k0.x), f2bf(k0.y), f2bf(k0.z), f2bf(k0.w),
                 f2bf(k1.x), f2bf(k1.y), f2bf(k1.z), f2bf(k1.w)};
    *(bf16x8*)&Kbf[((size_t)h * MT + t) * 8] = kv;
    float4 v0 = *(const float4*)(src + 128), v1 = *(const float4*)(src + 132);
    Vtb[((size_t)h * 8 + 0) * MT + t] = f2bf(v0.x);
    Vtb[((size_t)h * 8 + 1) * MT + t] = f2bf(v0.y);
    Vtb[((size_t)h * 8 + 2) * MT + t] = f2bf(v0.z);
    Vtb[((size_t)h * 8 + 3) * MT + t] = f2bf(v0.w);
    Vtb[((size_t)h * 8 + 4) * MT + t] = f2bf(v1.x);
    Vtb[((size_t)h * 8 + 5) * MT + t] = f2bf(v1.y);
    Vtb[((size_t)h * 8 + 6) * MT + t] = f2bf(v1.z);
    Vtb[((size_t)h * 8 + 7) * MT + t] = f2bf(v1.w);
  }
}

// ---------------------------------------------------------------- MFMA flash attention
// grid (64, 8): block = 64 queries x 1 head, 4 waves x 16 queries.
// K-tile = 256 keys; staging = pure bf16x8 loads + b128 LDS stores.
__global__ __launch_bounds__(256) void attn_kernel(const short* __restrict__ Qbf,
                                                   const short* __restrict__ Kbf,
                                                   const short* __restrict__ Vtb,
                                                   float* __restrict__ o_out) {
  const int h = blockIdx.y;
  const int qbase = blockIdx.x * 64;
  const int tid = threadIdx.x;
  const int wid = tid >> 6;
  const int lane = tid & 63;
  const int n = lane & 15;
  const int quad = lane >> 4;

  __shared__ short Klds[256 * 8];       // [key][ch]
  __shared__ short Vtlds[8 * 264];      // [ch][key], stride 264
  __shared__ short Plds[4][16 * 72];    // per-wave [query][key64], stride 72

  const bf16x8 zero8 = {0, 0, 0, 0, 0, 0, 0, 0};
  bf16x8 qb = zero8;
  if (quad == 0) qb = *(const bf16x8*)&Qbf[((size_t)h * MT + qbase + wid * 16 + n) * 8];

  float m_run = -1e30f, l_run = 0.f;
  f32x4 o_acc = {0.f, 0.f, 0.f, 0.f};

  for (int kt = 0; kt < 16; ++kt) {
    __syncthreads();
    *(bf16x8*)&Klds[tid * 8] = *(const bf16x8*)&Kbf[((size_t)h * MT + kt * 256 + tid) * 8];
    *(bf16x8*)&Vtlds[(tid >> 5) * 264 + (tid & 31) * 8] =
        *(const bf16x8*)&Vtb[((size_t)h * 8 + (tid >> 5)) * MT + kt * 256 + (tid & 31) * 8];
    __syncthreads();

#pragma unroll
    for (int sub = 0; sub < 4; ++sub) {
      const short* kbase = &Klds[sub * 64 * 8];
      f32x4 s[4];
#pragma unroll
      for (int mt = 0; mt < 4; ++mt) {
        bf16x8 ka = zero8;
        if (quad == 0) ka = *(const bf16x8*)&kbase[(mt * 16 + n) * 8];
        f32x4 zf = {0.f, 0.f, 0.f, 0.f};
        s[mt] = __builtin_amdgcn_mfma_f32_16x16x32_bf16(ka, qb, zf, 0, 0, 0);
      }

      float tmax = -1e30f;
#pragma unroll
      for (int mt = 0; mt < 4; ++mt)
#pragma unroll
        for (int r = 0; r < 4; ++r) tmax = fmaxf(tmax, s[mt][r]);
      tmax = fmaxf(tmax, __shfl_xor(tmax, 16, 64));
      tmax = fmaxf(tmax, __shfl_xor(tmax, 32, 64));

      float mn = fmaxf(m_run, tmax);
      float f = __expf(m_run - mn);
      m_run = mn;
      l_run *= f;
#pragma unroll
      for (int r = 0; r < 4; ++r) o_acc[r] *= f;

      float tsum = 0.f;
      short* pw = &Plds[wid][n * 72 + quad * 4];
#pragma unroll
      for (int mt = 0; mt < 4; ++mt) {
        float p0 = __expf(s[mt][0] - mn), p1 = __expf(s[mt][1] - mn);
        float p2 = __expf(s[mt][2] - mn), p3 = __expf(s[mt][3] - mn);
        tsum += (p0 + p1) + (p2 + p3);
        bf16x4 pv = {f2bf(p0), f2bf(p1), f2bf(p2), f2bf(p3)};
        *(bf16x4*)(pw + mt * 16) = pv;
      }
      tsum += __shfl_xor(tsum, 16, 64);
      tsum += __shfl_xor(tsum, 32, 64);
      l_run += tsum;

#pragma unroll
      for (int c = 0; c < 2; ++c) {
        bf16x8 va = zero8;
        if (n < 8) va = *(const bf16x8*)&Vtlds[n * 264 + sub * 64 + c * 32 + quad * 8];
        bf16x8 pb = *(const bf16x8*)&Plds[wid][n * 72 + c * 32 + quad * 8];
        o_acc = __builtin_amdgcn_mfma_f32_16x16x32_bf16(va, pb, o_acc, 0, 0, 0);
      }
    }
  }

  float inv = 1.0f / l_run;
  if (quad < 2) {
    float4 val = {o_acc[0] * inv, o_acc[1] * inv, o_acc[2] * inv, o_acc[3] * inv};
    *(float4*)&o_out[(size_t)(qbase + wid * 16 + n) * DM + h * 8 + quad * 4] = val;
  }
}

// ---------------------------------------------------------------- o-proj + residual + LN1
__global__ __launch_bounds__(64) void oproj_ln_kernel(const float* __restrict__ o_in,
                                                      float* __restrict__ x,
                                                      const float* __restrict__ Wt,
                                                      const float* __restrict__ B,
                                                      const float* __restrict__ g,
                                                      const float* __restrict__ b) {
  const int t0 = blockIdx.x * 4;
  const int d = threadIdx.x;
  __shared__ float orow[4][DM];
  ((float4*)orow)[d] = ((const float4*)(o_in + (size_t)t0 * DM))[d];
  __syncthreads();
  float acc0 = B[d], acc1 = acc0, acc2 = acc0, acc3 = acc0;
#pragma unroll 8
  for (int k4 = 0; k4 < 16; ++k4) {
    float w0 = Wt[(k4 * 4 + 0) * 64 + d];
    float w1 = Wt[(k4 * 4 + 1) * 64 + d];
    float w2 = Wt[(k4 * 4 + 2) * 64 + d];
    float w3 = Wt[(k4 * 4 + 3) * 64 + d];
    float4 a = *(const float4*)&orow[0][k4 * 4];
    acc0 += a.x * w0 + a.y * w1 + a.z * w2 + a.w * w3;
    float4 bb = *(const float4*)&orow[1][k4 * 4];
    acc1 += bb.x * w0 + bb.y * w1 + bb.z * w2 + bb.w * w3;
    float4 c = *(const float4*)&orow[2][k4 * 4];
    acc2 += c.x * w0 + c.y * w1 + c.z * w2 + c.w * w3;
    float4 e = *(const float4*)&orow[3][k4 * 4];
    acc3 += e.x * w0 + e.y * w1 + e.z * w2 + e.w * w3;
  }
  float accs[4] = {acc0, acc1, acc2, acc3};
#pragma unroll
  for (int t = 0; t < 4; ++t) {
    float hv = x[(size_t)(t0 + t) * DM + d] + accs[t];
    float mu = wave_sum64(hv) * (1.0f / DM);
    float dv = hv - mu;
    float var = wave_sum64(dv * dv) * (1.0f / DM);
    x[(size_t)(t0 + t) * DM + d] = dv * rsqrtf(var + LN_EPS) * g[d] + b[d];
  }
}

// ---------------------------------------------------------------- ff1 = relu(x @ W^T + b)
__global__ __launch_bounds__(256) void ff1_kernel(const float* __restrict__ x,
                                                  const float* __restrict__ Wt,
                                                  const float* __restrict__ B,
                                                  float* __restrict__ ff) {
  const int t0 = blockIdx.x * 4;
  const int o = threadIdx.x;
  __shared__ float xr[4][DM];
  if (o < 64) ((float4*)xr)[o] = ((const float4*)(x + (size_t)t0 * DM))[o];
  __syncthreads();
  float acc0 = B[o], acc1 = acc0, acc2 = acc0, acc3 = acc0;
#pragma unroll 8
  for (int k4 = 0; k4 < 16; ++k4) {
    float w0 = Wt[(k4 * 4 + 0) * 256 + o];
    float w1 = Wt[(k4 * 4 + 1) * 256 + o];
    float w2 = Wt[(k4 * 4 + 2) * 256 + o];
    float w3 = Wt[(k4 * 4 + 3) * 256 + o];
    float4 a = *(const float4*)&xr[0][k4 * 4];
    acc0 += a.x * w0 + a.y * w1 + a.z * w2 + a.w * w3;
    float4 b = *(const float4*)&xr[1][k4 * 4];
    acc1 += b.x * w0 + b.y * w1 + b.z * w2 + b.w * w3;
    float4 c = *(const float4*)&xr[2][k4 * 4];
    acc2 += c.x * w0 + c.y * w1 + c.z * w2 + c.w * w3;
    float4 e = *(const float4*)&xr[3][k4 * 4];
    acc3 += e.x * w0 + e.y * w1 + e.z * w2 + e.w * w3;
  }
  ff[(size_t)(t0 + 0) * DFF + o] = fmaxf(acc0, 0.0f);
  ff[(size_t)(t0 + 1) * DFF + o] = fmaxf(acc1, 0.0f);
  ff[(size_t)(t0 + 2) * DFF + o] = fmaxf(acc2, 0.0f);
  ff[(size_t)(t0 + 3) * DFF + o] = fmaxf(acc3, 0.0f);
}

// ---------------------------------------------------------------- ff2 + residual + LN2
__global__ __launch_bounds__(64) void ff2_ln_kernel(const float* __restrict__ ff,
                                                    float* __restrict__ x,
                                                    const float* __restrict__ Wt,
                                                    const float* __restrict__ B,
                                                    const float* __restrict__ g,
                                                    const float* __restrict__ b) {
  const int t0 = blockIdx.x * 4;
  const int d = threadIdx.x;
  __shared__ float fr[4][DFF];
  for (int e = d; e < 256; e += 64)
    ((float4*)fr)[e] = ((const float4*)(ff + (size_t)t0 * DFF))[e];
  __syncthreads();
  float acc0 = B[d], acc1 = acc0, acc2 = acc0, acc3 = acc0;
#pragma unroll 8
  for (int k4 = 0; k4 < 64; ++k4) {
    float w0 = Wt[(k4 * 4 + 0) * 64 + d];
    float w1 = Wt[(k4 * 4 + 1) * 64 + d];
    float w2 = Wt[(k4 * 4 + 2) * 64 + d];
    float w3 = Wt[(k4 * 4 + 3) * 64 + d];
    float4 a = *(const float4*)&fr[0][k4 * 4];
    acc0 += a.x * w0 + a.y * w1 + a.z * w2 + a.w * w3;
    float4 bb = *(const float4*)&fr[1][k4 * 4];
    acc1 += bb.x * w0 + bb.y * w1 + bb.z * w2 + bb.w * w3;
    float4 c = *(const float4*)&fr[2][k4 * 4];
    acc2 += c.x * w0 + c.y * w1 + c.z * w2 + c.w * w3;
    float4 e = *(const float4*)&fr[3][k4 * 4];
    acc3 += e.x * w0 + e.y * w1 + e.z * w2 + e.w * w3;
  }
  float accs[4] = {acc0, acc1, acc2, acc3};
#pragma unroll
  for (int t = 0; t < 4; ++t) {
    float hv = x[(size_t)(t0 + t) * DM + d] + accs[t];
    float mu = wave_sum64(hv) * (1.0f / DM);
    float dv = hv - mu;
    float var = wave_sum64(dv * dv) * (1.0f / DM);
    x[(size_t)(t0 + t) * DM + d] = dv * rsqrtf(var + LN_EPS) * g[d] + b[d];
  }
}

// ---------------------------------------------------------------- prune -> d_out
__global__ void prune_kernel(const float* __restrict__ x, const float* __restrict__ mask,
                             float* __restrict__ out) {
  int i = blockIdx.x * blockDim.x + threadIdx.x;
  if (i < MT * DM) out[i] = x[i] * mask[i & (DM - 1)];
}

// ---------------------------------------------------------------- row norms
__global__ __launch_bounds__(64) void norms_kernel(const float* __restrict__ xm,
                                                   const float* __restrict__ rgb,
                                                   float* __restrict__ nrm) {
  const int row = blockIdx.x;
  const int d = threadIdx.x;
  const float* src = (row < MT) ? (xm + (size_t)row * DM) : (rgb + (size_t)(row - MT) * DM);
  float v = src[d];
  float s = wave_sum64(v * v);
  if (d == 0) nrm[row] = s;
}

// ---------------------------------------------------------------- fp32 -> bf16 convert
__global__ void convert_bf16_kernel(const float* __restrict__ in, short* __restrict__ outb,
                                    int n8) {
  int i = blockIdx.x * blockDim.x + threadIdx.x;
  if (i < n8) {
    float4 a = ((const float4*)in)[i * 2];
    float4 b = ((const float4*)in)[i * 2 + 1];
    bf16x8 v = {f2bf(a.x), f2bf(a.y), f2bf(a.z), f2bf(a.w),
                f2bf(b.x), f2bf(b.y), f2bf(b.z), f2bf(b.w)};
    *(bf16x8*)&outb[(size_t)i * 8] = v;
  }
}

// ---------------------------------------------------------------- MMD via MFMA, no LDS
// grid (64,64,3); block 256 (4 waves). Fragments loaded directly from bf16
// global (L2-hot). Block partial -> partials[p*4096 + by*64 + bx]. No atomics.
__global__ __launch_bounds__(256) void mmd_kernel(const short* __restrict__ xmb,
                                                  const short* __restrict__ rgbb,
                                                  const float* __restrict__ nrm,
                                                  float* __restrict__ partials) {
  const int p = blockIdx.z;
  const short* A = (p == 1) ? rgbb : xmb;
  const short* B = (p == 0) ? xmb : rgbb;
  const float* nA = (p == 1) ? (nrm + MT) : nrm;
  const float* nB = (p == 0) ? nrm : (nrm + MT);
  const int i0 = blockIdx.x * 64;
  const int j0 = blockIdx.y * 64;
  const int tid = threadIdx.x;
  const int wid = tid >> 6;
  const int lane = tid & 63;
  const int n = lane & 15;
  const int quad = lane >> 4;

  const int arow = i0 + wid * 16 + n;
  bf16x8 a0 = *(const bf16x8*)&A[(size_t)arow * DM + quad * 8];
  bf16x8 a1 = *(const bf16x8*)&A[(size_t)arow * DM + 32 + quad * 8];
  float na[4];
#pragma unroll
  for (int r = 0; r < 4; ++r) na[r] = nA[i0 + wid * 16 + quad * 4 + r];

  float local = 0.f;
#pragma unroll
  for (int nt = 0; nt < 4; ++nt) {
    const int brow = j0 + nt * 16 + n;
    bf16x8 b0 = *(const bf16x8*)&B[(size_t)brow * DM + quad * 8];
    bf16x8 b1 = *(const bf16x8*)&B[(size_t)brow * DM + 32 + quad * 8];
    f32x4 zf = {0.f, 0.f, 0.f, 0.f};
    f32x4 d4 = __builtin_amdgcn_mfma_f32_16x16x32_bf16(a0, b0, zf, 0, 0, 0);
    d4 = __builtin_amdgcn_mfma_f32_16x16x32_bf16(a1, b1, d4, 0, 0, 0);
    float nb = nB[j0 + nt * 16 + n];
#pragma unroll
    for (int r = 0; r < 4; ++r) {
      float dist = na[r] + nb - 2.0f * d4[r];
      local += __expf(-0.5f * dist);
    }
  }

  float tot = wave_sum64(local);
  __shared__ float wpart[4];
  if (lane == 0) wpart[wid] = tot;
  __syncthreads();
  if (tid == 0)
    partials[(size_t)p * 4096 + blockIdx.y * 64 + blockIdx.x] =
        wpart[0] + wpart[1] + wpart[2] + wpart[3];
}

// ---------------------------------------------------------------- reduce partials
__global__ __launch_bounds__(256) void reduce_kernel(const float* __restrict__ partials,
                                                     float* __restrict__ acc) {
  const int p = blockIdx.x;
  const int tid = threadIdx.x;
  float s = 0.f;
  for (int i = tid; i < 4096; i += 256) s += partials[(size_t)p * 4096 + i];
  s = wave_sum64(s);
  __shared__ float wpart[4];
  if ((tid & 63) == 0) wpart[tid >> 6] = s;
  __syncthreads();
  if (tid == 0) acc[p] = wpart[0] + wpart[1] + wpart[2] + wpart[3];
}

// ---------------------------------------------------------------- finalize scalar
__global__ void finalize_kernel(const float* __restrict__ acc, float* __restrict__ out) {
  if (threadIdx.x == 0 && blockIdx.x == 0) {
    const float invn = 1.0f / ((float)MT * (float)MT);
    out[0] = (acc[0] + acc[1] - 2.0f * acc[2]) * invn;
  }
}

// ================================================================ launcher
extern "C" void kernel_launch(void* const* d_in, const int* in_sizes, int n_in,
                              void* d_out, int out_size, void* d_ws, size_t ws_size,
                              hipStream_t stream) {
  const float* hsi  = (const float*)d_in[0];
  const float* rgb  = (const float*)d_in[1];
  const float* inw  = (const float*)d_in[2];
  const float* inb  = (const float*)d_in[3];
  const float* ow   = (const float*)d_in[4];
  const float* obv  = (const float*)d_in[5];
  const float* l1w  = (const float*)d_in[6];
  const float* l1b  = (const float*)d_in[7];
  const float* l2w  = (const float*)d_in[8];
  const float* l2b  = (const float*)d_in[9];
  const float* n1w  = (const float*)d_in[10];
  const float* n1b  = (const float*)d_in[11];
  const float* n2w  = (const float*)d_in[12];
  const float* n2b  = (const float*)d_in[13];
  const float* mask = (const float*)d_in[14];
  float* out = (float*)d_out;

  float* ws    = (float*)d_ws;
  float* x     = ws;                    // 262144
  float* qkv   = ws + 262144;           // 786432
  float* ao    = ws + 1048576;          // 262144
  float* ffb   = ws + 1310720;          // 1048576
  float* nrm   = ws + 2359296;          // 8192
  float* accp  = ws + 2367488;          // 3 (padded to 64)
  float* parts = ws + 2367552;          // 12288
  short* xmb   = (short*)(ws + 2379840);  // 262144 shorts = 131072 floats
  short* rgbb  = (short*)(ws + 2510912);  // 262144 shorts
  short* Qbf   = (short*)(ws + 2641984);  // 262144 shorts
  short* Kbf   = (short*)(ws + 2773056);  // 262144 shorts
  short* Vtb   = (short*)(ws + 2904128);  // 262144 shorts  (end ~3035200 floats = 12.1 MB)

  // transposed weights live in d_out (dead until prune_kernel)
  float* Wti = out;                    // 4*64*192
  float* Wto = out + 49152;            // 4*64*64
  float* Wt1 = out + 65536;            // 4*64*256
  float* Wt2 = out + 131072;           // 4*256*64

  transpose_kernel<<<dim3(2, 6, 4), 256, 0, stream>>>(inw, Wti, 192, 64);
  transpose_kernel<<<dim3(2, 2, 4), 256, 0, stream>>>(ow,  Wto, 64, 64);
  transpose_kernel<<<dim3(2, 8, 4), 256, 0, stream>>>(l1w, Wt1, 256, 64);
  transpose_kernel<<<dim3(8, 2, 4), 256, 0, stream>>>(l2w, Wt2, 64, 256);

  copy_kernel<<<256, 256, 0, stream>>>((const float4*)hsi, (float4*)x, MT * DM / 4);

  for (int i = 0; i < NLAYER; ++i) {
    qkv_kernel<<<MT / 4, 192, 0, stream>>>(x, Wti + (size_t)i * 192 * DM, inb + (size_t)i * 192, qkv);
    attn_pack_kernel<<<MT / 256, 256, 0, stream>>>(qkv, Qbf, Kbf, Vtb);
    attn_kernel<<<dim3(MT / 64, NHEAD), 256, 0, stream>>>(Qbf, Kbf, Vtb, ao);
    oproj_ln_kernel<<<MT / 4, 64, 0, stream>>>(ao, x, Wto + (size_t)i * DM * DM, obv + (size_t)i * DM,
                                               n1w + (size_t)i * DM, n1b + (size_t)i * DM);
    ff1_kernel<<<MT / 4, 256, 0, stream>>>(x, Wt1 + (size_t)i * DFF * DM, l1b + (size_t)i * DFF, ffb);
    ff2_ln_kernel<<<MT / 4, 64, 0, stream>>>(ffb, x, Wt2 + (size_t)i * DM * DFF, l2b + (size_t)i * DM,
                                             n2w + (size_t)i * DM, n2b + (size_t)i * DM);
  }

  prune_kernel<<<(MT * DM + 255) / 256, 256, 0, stream>>>(x, mask, out);
  norms_kernel<<<2 * MT, 64, 0, stream>>>(out, rgb, nrm);
  convert_bf16_kernel<<<128, 256, 0, stream>>>(out, xmb, MT * DM / 8);
  convert_bf16_kernel<<<128, 256, 0, stream>>>(rgb, rgbb, MT * DM / 8);
  mmd_kernel<<<dim3(64, 64, 3), 256, 0, stream>>>(xmb, rgbb, nrm, parts);
  reduce_kernel<<<3, 256, 0, stream>>>(parts, accp);
  finalize_kernel<<<1, 64, 0, stream>>>(accp, out + (size_t)MT * DM);
}

// Round 6
// 420.074 us; speedup vs baseline: 5.4194x; 1.3495x over previous
//
#include <hip/hip_runtime.h>

#define MT 4096      // tokens
#define DM 64        // d_model
#define NHEAD 8
#define HDIM 8
#define DFF 256
#define NLAYER 4
#define LN_EPS 1e-5f

typedef __attribute__((ext_vector_type(8))) short bf16x8;
typedef __attribute__((ext_vector_type(4))) short bf16x4;
typedef __attribute__((ext_vector_type(4))) float f32x4;

__device__ __forceinline__ float wave_sum64(float v) {
#pragma unroll
  for (int m = 1; m < 64; m <<= 1) v += __shfl_xor(v, m, 64);
  return v;
}

__device__ __forceinline__ short f2bf(float x) {   // RNE float->bf16
  union { float f; unsigned u; } v; v.f = x;
  unsigned r = v.u + 0x7fffu + ((v.u >> 16) & 1u);
  return (short)(r >> 16);
}

// ---------------------------------------------------------------- copy x <- hsi
__global__ void copy_kernel(const float4* __restrict__ in, float4* __restrict__ out, int n4) {
  int i = blockIdx.x * blockDim.x + threadIdx.x;
  if (i < n4) out[i] = in[i];
}

// ---------------------------------------------------------------- all weight transposes in one kernel
// 192 tiles of 32x32. [0,48): inw 192x64; [48,64): ow 64x64; [64,128): l1w 256x64; [128,192): l2w 64x256.
__global__ void transpose_all_kernel(const float* __restrict__ inw, float* __restrict__ Wti,
                                     const float* __restrict__ ow,  float* __restrict__ Wto,
                                     const float* __restrict__ l1w, float* __restrict__ Wt1,
                                     const float* __restrict__ l2w, float* __restrict__ Wt2) {
  const int bid = blockIdx.x;
  const float* src; float* dst; int R, C, r0, c0;
  if (bid < 48) {
    int l = bid / 12, t = bid % 12;
    src = inw + (size_t)l * 12288; dst = Wti + (size_t)l * 12288;
    R = 192; C = 64; c0 = (t % 2) * 32; r0 = (t / 2) * 32;
  } else if (bid < 64) {
    int idx = bid - 48, l = idx / 4, t = idx % 4;
    src = ow + (size_t)l * 4096; dst = Wto + (size_t)l * 4096;
    R = 64; C = 64; c0 = (t % 2) * 32; r0 = (t / 2) * 32;
  } else if (bid < 128) {
    int idx = bid - 64, l = idx / 16, t = idx % 16;
    src = l1w + (size_t)l * 16384; dst = Wt1 + (size_t)l * 16384;
    R = 256; C = 64; c0 = (t % 2) * 32; r0 = (t / 2) * 32;
  } else {
    int idx = bid - 128, l = idx / 16, t = idx % 16;
    src = l2w + (size_t)l * 16384; dst = Wt2 + (size_t)l * 16384;
    R = 64; C = 256; c0 = (t % 8) * 32; r0 = (t / 8) * 32;
  }
  __shared__ float tl[32][33];
  const int tx = threadIdx.x & 31, ty = threadIdx.x >> 5;
  for (int rr = ty; rr < 32; rr += 8)
    tl[rr][tx] = src[(size_t)(r0 + rr) * C + c0 + tx];
  __syncthreads();
  for (int cc = ty; cc < 32; cc += 8)
    dst[(size_t)(c0 + cc) * R + r0 + tx] = tl[tx][cc];
}

// ---------------------------------------------------------------- qkv -> packed bf16 Q/K/V^T
// Wt: [64][192] k-major. Block = 4 tokens x 192 outputs.
// Qbf/Kbf: [h][t][8] (Q pre-scaled); Vtb: [h*8+ch][t]
__global__ __launch_bounds__(192) void qkv_kernel(const float* __restrict__ x,
                                                  const float* __restrict__ Wt,
                                                  const float* __restrict__ B,
                                                  short* __restrict__ Qbf,
                                                  short* __restrict__ Kbf,
                                                  short* __restrict__ Vtb) {
  const int t0 = blockIdx.x * 4;
  const int o = threadIdx.x;
  __shared__ float xr[4][DM];
  for (int e = o; e < 64; e += 192)
    ((float4*)xr)[e] = ((const float4*)(x + (size_t)t0 * DM))[e];
  __syncthreads();
  float acc0 = B[o], acc1 = acc0, acc2 = acc0, acc3 = acc0;
#pragma unroll 8
  for (int k4 = 0; k4 < 16; ++k4) {
    float w0 = Wt[(k4 * 4 + 0) * 192 + o];
    float w1 = Wt[(k4 * 4 + 1) * 192 + o];
    float w2 = Wt[(k4 * 4 + 2) * 192 + o];
    float w3 = Wt[(k4 * 4 + 3) * 192 + o];
    float4 a = *(const float4*)&xr[0][k4 * 4];
    acc0 += a.x * w0 + a.y * w1 + a.z * w2 + a.w * w3;
    float4 b = *(const float4*)&xr[1][k4 * 4];
    acc1 += b.x * w0 + b.y * w1 + b.z * w2 + b.w * w3;
    float4 c = *(const float4*)&xr[2][k4 * 4];
    acc2 += c.x * w0 + c.y * w1 + c.z * w2 + c.w * w3;
    float4 d = *(const float4*)&xr[3][k4 * 4];
    acc3 += d.x * w0 + d.y * w1 + d.z * w2 + d.w * w3;
  }
  if (o < 128) {
    const int c = o & 63, hh = c >> 3, ch = c & 7;
    short* dst = (o < 64) ? Qbf : Kbf;
    const float sc = (o < 64) ? 0.35355339059327373f : 1.0f;
    dst[((size_t)hh * MT + t0 + 0) * 8 + ch] = f2bf(acc0 * sc);
    dst[((size_t)hh * MT + t0 + 1) * 8 + ch] = f2bf(acc1 * sc);
    dst[((size_t)hh * MT + t0 + 2) * 8 + ch] = f2bf(acc2 * sc);
    dst[((size_t)hh * MT + t0 + 3) * 8 + ch] = f2bf(acc3 * sc);
  } else {
    const int c = o - 128;
    bf16x4 v = {f2bf(acc0), f2bf(acc1), f2bf(acc2), f2bf(acc3)};
    *(bf16x4*)&Vtb[(size_t)c * MT + t0] = v;
  }
}

// ---------------------------------------------------------------- MFMA flash attention, no-max, key-split
// grid (64, 8, 2): block = 64 queries x 1 head x 2048 keys; 4 waves x 16 queries.
// No max subtraction (scores bounded |s|<~2). l computed by MFMA via ones-row
// (channel 8) of V^T: accumulator row 8 = sum(exp). Partial (unscaled o, l)
// written per z; combined in oproj.
__global__ __launch_bounds__(256) void attn_kernel(const short* __restrict__ Qbf,
                                                   const short* __restrict__ Kbf,
                                                   const short* __restrict__ Vtb,
                                                   float* __restrict__ pbuf,
                                                   float* __restrict__ lbuf) {
  const int h = blockIdx.y;
  const int qbase = blockIdx.x * 64;
  const int z = blockIdx.z;
  const int tid = threadIdx.x;
  const int wid = tid >> 6;
  const int lane = tid & 63;
  const int n = lane & 15;
  const int quad = lane >> 4;

  __shared__ short Klds[256 * 8];       // [key][ch]
  __shared__ short Vtlds[9 * 264];      // [ch][key] + ones row 8, stride 264
  __shared__ short Plds[4][16 * 72];    // per-wave [query][key64], stride 72

  if (tid < 32) {
    bf16x8 ones = {0x3F80, 0x3F80, 0x3F80, 0x3F80, 0x3F80, 0x3F80, 0x3F80, 0x3F80};
    *(bf16x8*)&Vtlds[8 * 264 + tid * 8] = ones;
  }

  const bf16x8 zero8 = {0, 0, 0, 0, 0, 0, 0, 0};
  bf16x8 qb = zero8;
  if (quad == 0) qb = *(const bf16x8*)&Qbf[((size_t)h * MT + qbase + wid * 16 + n) * 8];

  f32x4 o_acc = {0.f, 0.f, 0.f, 0.f};

  for (int kt = 0; kt < 8; ++kt) {
    const int k0 = z * 2048 + kt * 256;
    __syncthreads();
    *(bf16x8*)&Klds[tid * 8] = *(const bf16x8*)&Kbf[((size_t)h * MT + k0 + tid) * 8];
    *(bf16x8*)&Vtlds[(tid >> 5) * 264 + (tid & 31) * 8] =
        *(const bf16x8*)&Vtb[((size_t)h * 8 + (tid >> 5)) * MT + k0 + (tid & 31) * 8];
    __syncthreads();

#pragma unroll
    for (int sub = 0; sub < 4; ++sub) {
      const short* kbase = &Klds[sub * 64 * 8];
      f32x4 s[4];
#pragma unroll
      for (int mt = 0; mt < 4; ++mt) {
        bf16x8 ka = zero8;
        if (quad == 0) ka = *(const bf16x8*)&kbase[(mt * 16 + n) * 8];
        f32x4 zf = {0.f, 0.f, 0.f, 0.f};
        s[mt] = __builtin_amdgcn_mfma_f32_16x16x32_bf16(ka, qb, zf, 0, 0, 0);
      }

      short* pw = &Plds[wid][n * 72 + quad * 4];
#pragma unroll
      for (int mt = 0; mt < 4; ++mt) {
        float p0 = __expf(s[mt][0]), p1 = __expf(s[mt][1]);
        float p2 = __expf(s[mt][2]), p3 = __expf(s[mt][3]);
        bf16x4 pv = {f2bf(p0), f2bf(p1), f2bf(p2), f2bf(p3)};
        *(bf16x4*)(pw + mt * 16) = pv;
      }

#pragma unroll
      for (int c = 0; c < 2; ++c) {
        bf16x8 va = zero8;
        if (n < 9) va = *(const bf16x8*)&Vtlds[n * 264 + sub * 64 + c * 32 + quad * 8];
        bf16x8 pb = *(const bf16x8*)&Plds[wid][n * 72 + c * 32 + quad * 8];
        o_acc = __builtin_amdgcn_mfma_f32_16x16x32_bf16(va, pb, o_acc, 0, 0, 0);
      }
    }
  }

  // rows: quad*4+r = channel; row 8 (quad==2, r==0) = l
  const int tok = qbase + wid * 16 + n;
  if (quad < 2) {
    float4 val = {o_acc[0], o_acc[1], o_acc[2], o_acc[3]};
    *(float4*)&pbuf[((size_t)z * MT + tok) * DM + h * 8 + quad * 4] = val;
  }
  if (quad == 2) lbuf[(size_t)z * MT * 8 + (size_t)tok * 8 + h] = o_acc[0];
}

// ---------------------------------------------------------------- combine + o-proj + residual + LN1
__global__ __launch_bounds__(64) void oproj_ln_kernel(const float* __restrict__ pbuf,
                                                      const float* __restrict__ lbuf,
                                                      float* __restrict__ x,
                                                      const float* __restrict__ Wt,
                                                      const float* __restrict__ B,
                                                      const float* __restrict__ g,
                                                      const float* __restrict__ b) {
  const int t0 = blockIdx.x * 4;
  const int d = threadIdx.x;
  const int h = d >> 3;
  __shared__ float orow[4][DM];
#pragma unroll
  for (int tt = 0; tt < 4; ++tt) {
    float o0 = pbuf[(size_t)(t0 + tt) * DM + d];
    float o1 = pbuf[(size_t)MT * DM + (size_t)(t0 + tt) * DM + d];
    float l = lbuf[(size_t)(t0 + tt) * 8 + h] + lbuf[(size_t)MT * 8 + (size_t)(t0 + tt) * 8 + h];
    orow[tt][d] = (o0 + o1) / l;
  }
  __syncthreads();
  float acc0 = B[d], acc1 = acc0, acc2 = acc0, acc3 = acc0;
#pragma unroll 8
  for (int k4 = 0; k4 < 16; ++k4) {
    float w0 = Wt[(k4 * 4 + 0) * 64 + d];
    float w1 = Wt[(k4 * 4 + 1) * 64 + d];
    float w2 = Wt[(k4 * 4 + 2) * 64 + d];
    float w3 = Wt[(k4 * 4 + 3) * 64 + d];
    float4 a = *(const float4*)&orow[0][k4 * 4];
    acc0 += a.x * w0 + a.y * w1 + a.z * w2 + a.w * w3;
    float4 bb = *(const float4*)&orow[1][k4 * 4];
    acc1 += bb.x * w0 + bb.y * w1 + bb.z * w2 + bb.w * w3;
    float4 c = *(const float4*)&orow[2][k4 * 4];
    acc2 += c.x * w0 + c.y * w1 + c.z * w2 + c.w * w3;
    float4 e = *(const float4*)&orow[3][k4 * 4];
    acc3 += e.x * w0 + e.y * w1 + e.z * w2 + e.w * w3;
  }
  float accs[4] = {acc0, acc1, acc2, acc3};
#pragma unroll
  for (int t = 0; t < 4; ++t) {
    float hv = x[(size_t)(t0 + t) * DM + d] + accs[t];
    float mu = wave_sum64(hv) * (1.0f / DM);
    float dv = hv - mu;
    float var = wave_sum64(dv * dv) * (1.0f / DM);
    x[(size_t)(t0 + t) * DM + d] = dv * rsqrtf(var + LN_EPS) * g[d] + b[d];
  }
}

// ---------------------------------------------------------------- fused FFN: relu(x@W1^T+b1)@W2^T+b2 + res + LN2
// Block = 4 tokens x 256 threads. Phase 1: thread o -> ff1 out o for 4 tokens.
// Phase 2: thread = (token t = o>>6, d = o&63); wave per token for LN.
__global__ __launch_bounds__(256) void ffn_kernel(float* __restrict__ x,
                                                  const float* __restrict__ Wt1,
                                                  const float* __restrict__ B1,
                                                  const float* __restrict__ Wt2,
                                                  const float* __restrict__ B2,
                                                  const float* __restrict__ g,
                                                  const float* __restrict__ b) {
  const int t0 = blockIdx.x * 4;
  const int o = threadIdx.x;
  __shared__ float xr[4][DM];
  __shared__ float fr[4][DFF];
  if (o < 64) ((float4*)xr)[o] = ((const float4*)(x + (size_t)t0 * DM))[o];
  __syncthreads();
  {
    float acc0 = B1[o], acc1 = acc0, acc2 = acc0, acc3 = acc0;
#pragma unroll 8
    for (int k4 = 0; k4 < 16; ++k4) {
      float w0 = Wt1[(k4 * 4 + 0) * 256 + o];
      float w1 = Wt1[(k4 * 4 + 1) * 256 + o];
      float w2 = Wt1[(k4 * 4 + 2) * 256 + o];
      float w3 = Wt1[(k4 * 4 + 3) * 256 + o];
      float4 a = *(const float4*)&xr[0][k4 * 4];
      acc0 += a.x * w0 + a.y * w1 + a.z * w2 + a.w * w3;
      float4 bb = *(const float4*)&xr[1][k4 * 4];
      acc1 += bb.x * w0 + bb.y * w1 + bb.z * w2 + bb.w * w3;
      float4 c = *(const float4*)&xr[2][k4 * 4];
      acc2 += c.x * w0 + c.y * w1 + c.z * w2 + c.w * w3;
      float4 e = *(const float4*)&xr[3][k4 * 4];
      acc3 += e.x * w0 + e.y * w1 + e.z * w2 + e.w * w3;
    }
    fr[0][o] = fmaxf(acc0, 0.0f);
    fr[1][o] = fmaxf(acc1, 0.0f);
    fr[2][o] = fmaxf(acc2, 0.0f);
    fr[3][o] = fmaxf(acc3, 0.0f);
  }
  __syncthreads();
  const int t = o >> 6, d = o & 63;
  float facc = B2[d];
#pragma unroll 8
  for (int k4 = 0; k4 < 64; ++k4) {
    float w0 = Wt2[(k4 * 4 + 0) * 64 + d];
    float w1 = Wt2[(k4 * 4 + 1) * 64 + d];
    float w2 = Wt2[(k4 * 4 + 2) * 64 + d];
    float w3 = Wt2[(k4 * 4 + 3) * 64 + d];
    float4 a = *(const float4*)&fr[t][k4 * 4];
    facc += a.x * w0 + a.y * w1 + a.z * w2 + a.w * w3;
  }
  float hv = xr[t][d] + facc;
  float mu = wave_sum64(hv) * (1.0f / DM);
  float dv = hv - mu;
  float var = wave_sum64(dv * dv) * (1.0f / DM);
  x[(size_t)(t0 + t) * DM + d] = dv * rsqrtf(var + LN_EPS) * g[d] + b[d];
}

// ---------------------------------------------------------------- prune + norms + bf16 convert
// grid 2048 x 256 (4 rows/block, wave per row); rows [0,MT)=x->out/xmb, [MT,2MT)=rgb->rgbb
__global__ __launch_bounds__(256) void pnc_kernel(const float* __restrict__ x,
                                                  const float* __restrict__ rgb,
                                                  const float* __restrict__ mask,
                                                  float* __restrict__ out,
                                                  short* __restrict__ xmb,
                                                  short* __restrict__ rgbb,
                                                  float* __restrict__ nrm) {
  const int row = blockIdx.x * 4 + (threadIdx.x >> 6);
  const int d = threadIdx.x & 63;
  float v;
  if (row < MT) {
    v = x[(size_t)row * DM + d] * mask[d];
    out[(size_t)row * DM + d] = v;
    xmb[(size_t)row * DM + d] = f2bf(v);
  } else {
    v = rgb[(size_t)(row - MT) * DM + d];
    rgbb[(size_t)(row - MT) * DM + d] = f2bf(v);
  }
  float s = wave_sum64(v * v);
  if (d == 0) nrm[row] = s;
}

// ---------------------------------------------------------------- MMD via MFMA, no LDS
__global__ __launch_bounds__(256) void mmd_kernel(const short* __restrict__ xmb,
                                                  const short* __restrict__ rgbb,
                                                  const float* __restrict__ nrm,
                                                  float* __restrict__ partials) {
  const int p = blockIdx.z;
  const short* A = (p == 1) ? rgbb : xmb;
  const short* B = (p == 0) ? xmb : rgbb;
  const float* nA = (p == 1) ? (nrm + MT) : nrm;
  const float* nB = (p == 0) ? nrm : (nrm + MT);
  const int i0 = blockIdx.x * 64;
  const int j0 = blockIdx.y * 64;
  const int tid = threadIdx.x;
  const int wid = tid >> 6;
  const int lane = tid & 63;
  const int n = lane & 15;
  const int quad = lane >> 4;

  const int arow = i0 + wid * 16 + n;
  bf16x8 a0 = *(const bf16x8*)&A[(size_t)arow * DM + quad * 8];
  bf16x8 a1 = *(const bf16x8*)&A[(size_t)arow * DM + 32 + quad * 8];
  float na[4];
#pragma unroll
  for (int r = 0; r < 4; ++r) na[r] = nA[i0 + wid * 16 + quad * 4 + r];

  float local = 0.f;
#pragma unroll
  for (int nt = 0; nt < 4; ++nt) {
    const int brow = j0 + nt * 16 + n;
    bf16x8 b0 = *(const bf16x8*)&B[(size_t)brow * DM + quad * 8];
    bf16x8 b1 = *(const bf16x8*)&B[(size_t)brow * DM + 32 + quad * 8];
    f32x4 zf = {0.f, 0.f, 0.f, 0.f};
    f32x4 d4 = __builtin_amdgcn_mfma_f32_16x16x32_bf16(a0, b0, zf, 0, 0, 0);
    d4 = __builtin_amdgcn_mfma_f32_16x16x32_bf16(a1, b1, d4, 0, 0, 0);
    float nb = nB[j0 + nt * 16 + n];
#pragma unroll
    for (int r = 0; r < 4; ++r) {
      float dist = na[r] + nb - 2.0f * d4[r];
      local += __expf(-0.5f * dist);
    }
  }

  float tot = wave_sum64(local);
  __shared__ float wpart[4];
  if (lane == 0) wpart[wid] = tot;
  __syncthreads();
  if (tid == 0)
    partials[(size_t)p * 4096 + blockIdx.y * 64 + blockIdx.x] =
        wpart[0] + wpart[1] + wpart[2] + wpart[3];
}

// ---------------------------------------------------------------- reduce + finalize (1 block)
__global__ __launch_bounds__(256) void reducefin_kernel(const float* __restrict__ partials,
                                                        float* __restrict__ out) {
  const int w = threadIdx.x >> 6, lane = threadIdx.x & 63;
  __shared__ float L[4];
  float s = 0.f;
  if (w < 3)
    for (int i = lane; i < 4096; i += 64) s += partials[(size_t)w * 4096 + i];
  s = wave_sum64(s);
  if (lane == 0) L[w] = s;
  __syncthreads();
  if (threadIdx.x == 0) {
    const float invn = 1.0f / ((float)MT * (float)MT);
    out[(size_t)MT * DM] = (L[0] + L[1] - 2.0f * L[2]) * invn;
  }
}

// ================================================================ launcher
extern "C" void kernel_launch(void* const* d_in, const int* in_sizes, int n_in,
                              void* d_out, int out_size, void* d_ws, size_t ws_size,
                              hipStream_t stream) {
  const float* hsi  = (const float*)d_in[0];
  const float* rgb  = (const float*)d_in[1];
  const float* inw  = (const float*)d_in[2];
  const float* inb  = (const float*)d_in[3];
  const float* ow   = (const float*)d_in[4];
  const float* obv  = (const float*)d_in[5];
  const float* l1w  = (const float*)d_in[6];
  const float* l1b  = (const float*)d_in[7];
  const float* l2w  = (const float*)d_in[8];
  const float* l2b  = (const float*)d_in[9];
  const float* n1w  = (const float*)d_in[10];
  const float* n1b  = (const float*)d_in[11];
  const float* n2w  = (const float*)d_in[12];
  const float* n2b  = (const float*)d_in[13];
  const float* mask = (const float*)d_in[14];
  float* out = (float*)d_out;

  float* ws    = (float*)d_ws;
  float* x     = ws;                       // 262144
  float* pbuf  = ws + 262144;              // 2 * 262144
  float* lbuf  = ws + 786432;              // 2 * 32768
  float* nrm   = ws + 851968;              // 8192
  float* parts = ws + 860224;              // 12288
  short* xmb   = (short*)(ws + 872512);    // 262144 shorts
  short* rgbb  = (short*)(ws + 1003584);   // 262144 shorts
  short* Qbf   = (short*)(ws + 1134656);   // 262144 shorts
  short* Kbf   = (short*)(ws + 1265728);   // 262144 shorts
  short* Vtb   = (short*)(ws + 1396800);   // 262144 shorts

  // transposed weights live in d_out (dead until pnc_kernel)
  float* Wti = out;                    // 4*64*192
  float* Wto = out + 49152;            // 4*64*64
  float* Wt1 = out + 65536;            // 4*64*256
  float* Wt2 = out + 131072;           // 4*256*64

  transpose_all_kernel<<<192, 256, 0, stream>>>(inw, Wti, ow, Wto, l1w, Wt1, l2w, Wt2);
  copy_kernel<<<256, 256, 0, stream>>>((const float4*)hsi, (float4*)x, MT * DM / 4);

  for (int i = 0; i < NLAYER; ++i) {
    qkv_kernel<<<MT / 4, 192, 0, stream>>>(x, Wti + (size_t)i * 192 * DM, inb + (size_t)i * 192,
                                           Qbf, Kbf, Vtb);
    attn_kernel<<<dim3(MT / 64, NHEAD, 2), 256, 0, stream>>>(Qbf, Kbf, Vtb, pbuf, lbuf);
    oproj_ln_kernel<<<MT / 4, 64, 0, stream>>>(pbuf, lbuf, x, Wto + (size_t)i * DM * DM,
                                               obv + (size_t)i * DM,
                                               n1w + (size_t)i * DM, n1b + (size_t)i * DM);
    ffn_kernel<<<MT / 4, 256, 0, stream>>>(x, Wt1 + (size_t)i * DFF * DM, l1b + (size_t)i * DFF,
                                           Wt2 + (size_t)i * DM * DFF, l2b + (size_t)i * DM,
                                           n2w + (size_t)i * DM, n2b + (size_t)i * DM);
  }

  pnc_kernel<<<2 * MT / 4, 256, 0, stream>>>(x, rgb, mask, out, xmb, rgbb, nrm);
  mmd_kernel<<<dim3(64, 64, 3), 256, 0, stream>>>(xmb, rgbb, nrm, parts);
  reducefin_kernel<<<1, 256, 0, stream>>>(parts, out);
}

// Round 7
// 375.378 us; speedup vs baseline: 6.0646x; 1.1191x over previous
//
#include <hip/hip_runtime.h>

#define MT 4096      // tokens
#define DM 64        // d_model
#define NHEAD 8
#define HDIM 8
#define DFF 256
#define NLAYER 4
#define LN_EPS 1e-5f

typedef __attribute__((ext_vector_type(8))) short bf16x8;
typedef __attribute__((ext_vector_type(4))) short bf16x4;
typedef __attribute__((ext_vector_type(4))) float f32x4;

__device__ __forceinline__ float wave_sum64(float v) {
#pragma unroll
  for (int m = 1; m < 64; m <<= 1) v += __shfl_xor(v, m, 64);
  return v;
}

__device__ __forceinline__ short f2bf(float x) {   // RNE float->bf16
  union { float f; unsigned u; } v; v.f = x;
  unsigned r = v.u + 0x7fffu + ((v.u >> 16) & 1u);
  return (short)(r >> 16);
}

// ---------------------------------------------------------------- transposes + rgb prep
// bid<192: weight transpose tiles; bid>=192: rgb rows -> rgbb + nrm[MT..2MT)
__global__ void prep_kernel(const float* __restrict__ inw, float* __restrict__ Wti,
                            const float* __restrict__ ow,  float* __restrict__ Wto,
                            const float* __restrict__ l1w, float* __restrict__ Wt1,
                            const float* __restrict__ l2w, float* __restrict__ Wt2,
                            const float* __restrict__ rgb, short* __restrict__ rgbb,
                            float* __restrict__ nrm) {
  const int bid = blockIdx.x;
  if (bid >= 192) {
    const int row = (bid - 192) * 4 + (threadIdx.x >> 6);
    const int d = threadIdx.x & 63;
    float v = rgb[(size_t)row * DM + d];
    rgbb[(size_t)row * DM + d] = f2bf(v);
    float s = wave_sum64(v * v);
    if (d == 0) nrm[MT + row] = s;
    return;
  }
  const float* src; float* dst; int R, C, r0, c0;
  if (bid < 48) {
    int l = bid / 12, t = bid % 12;
    src = inw + (size_t)l * 12288; dst = Wti + (size_t)l * 12288;
    R = 192; C = 64; c0 = (t % 2) * 32; r0 = (t / 2) * 32;
  } else if (bid < 64) {
    int idx = bid - 48, l = idx / 4, t = idx % 4;
    src = ow + (size_t)l * 4096; dst = Wto + (size_t)l * 4096;
    R = 64; C = 64; c0 = (t % 2) * 32; r0 = (t / 2) * 32;
  } else if (bid < 128) {
    int idx = bid - 64, l = idx / 16, t = idx % 16;
    src = l1w + (size_t)l * 16384; dst = Wt1 + (size_t)l * 16384;
    R = 256; C = 64; c0 = (t % 2) * 32; r0 = (t / 2) * 32;
  } else {
    int idx = bid - 128, l = idx / 16, t = idx % 16;
    src = l2w + (size_t)l * 16384; dst = Wt2 + (size_t)l * 16384;
    R = 64; C = 256; c0 = (t % 8) * 32; r0 = (t / 8) * 32;
  }
  __shared__ float tl[32][33];
  const int tx = threadIdx.x & 31, ty = threadIdx.x >> 5;
  for (int rr = ty; rr < 32; rr += 8)
    tl[rr][tx] = src[(size_t)(r0 + rr) * C + c0 + tx];
  __syncthreads();
  for (int cc = ty; cc < 32; cc += 8)
    dst[(size_t)(c0 + cc) * R + r0 + tx] = tl[tx][cc];
}

// ---------------------------------------------------------------- layer-0 qkv from hsi (+ x copy)
__global__ __launch_bounds__(192) void qkv0_kernel(const float* __restrict__ hsi,
                                                   const float* __restrict__ Wt,
                                                   const float* __restrict__ B,
                                                   float* __restrict__ x,
                                                   short* __restrict__ Qbf,
                                                   short* __restrict__ Kbf,
                                                   short* __restrict__ Vtb) {
  const int t0 = blockIdx.x * 4;
  const int o = threadIdx.x;
  __shared__ float xr[4][DM];
  for (int e = o; e < 64; e += 192) {
    float4 v = ((const float4*)(hsi + (size_t)t0 * DM))[e];
    ((float4*)xr)[e] = v;
    ((float4*)(x + (size_t)t0 * DM))[e] = v;
  }
  __syncthreads();
  float acc0 = B[o], acc1 = acc0, acc2 = acc0, acc3 = acc0;
#pragma unroll 8
  for (int k4 = 0; k4 < 16; ++k4) {
    float w0 = Wt[(k4 * 4 + 0) * 192 + o];
    float w1 = Wt[(k4 * 4 + 1) * 192 + o];
    float w2 = Wt[(k4 * 4 + 2) * 192 + o];
    float w3 = Wt[(k4 * 4 + 3) * 192 + o];
    float4 a = *(const float4*)&xr[0][k4 * 4];
    acc0 += a.x * w0 + a.y * w1 + a.z * w2 + a.w * w3;
    float4 b = *(const float4*)&xr[1][k4 * 4];
    acc1 += b.x * w0 + b.y * w1 + b.z * w2 + b.w * w3;
    float4 c = *(const float4*)&xr[2][k4 * 4];
    acc2 += c.x * w0 + c.y * w1 + c.z * w2 + c.w * w3;
    float4 d = *(const float4*)&xr[3][k4 * 4];
    acc3 += d.x * w0 + d.y * w1 + d.z * w2 + d.w * w3;
  }
  if (o < 128) {
    const int c = o & 63, hh = c >> 3, ch = c & 7;
    short* dst = (o < 64) ? Qbf : Kbf;
    const float sc = (o < 64) ? 0.35355339059327373f : 1.0f;
    dst[((size_t)hh * MT + t0 + 0) * 8 + ch] = f2bf(acc0 * sc);
    dst[((size_t)hh * MT + t0 + 1) * 8 + ch] = f2bf(acc1 * sc);
    dst[((size_t)hh * MT + t0 + 2) * 8 + ch] = f2bf(acc2 * sc);
    dst[((size_t)hh * MT + t0 + 3) * 8 + ch] = f2bf(acc3 * sc);
  } else {
    const int c = o - 128;
    bf16x4 v = {f2bf(acc0), f2bf(acc1), f2bf(acc2), f2bf(acc3)};
    *(bf16x4*)&Vtb[(size_t)c * MT + t0] = v;
  }
}

// ---------------------------------------------------------------- MFMA flash attention, no-max, z=4
__global__ __launch_bounds__(256) void attn_kernel(const short* __restrict__ Qbf,
                                                   const short* __restrict__ Kbf,
                                                   const short* __restrict__ Vtb,
                                                   float* __restrict__ pbuf,
                                                   float* __restrict__ lbuf) {
  const int h = blockIdx.y;
  const int qbase = blockIdx.x * 64;
  const int z = blockIdx.z;
  const int tid = threadIdx.x;
  const int wid = tid >> 6;
  const int lane = tid & 63;
  const int n = lane & 15;
  const int quad = lane >> 4;

  __shared__ short Klds[256 * 8];
  __shared__ short Vtlds[9 * 264];
  __shared__ short Plds[4][16 * 72];

  if (tid < 32) {
    bf16x8 ones = {0x3F80, 0x3F80, 0x3F80, 0x3F80, 0x3F80, 0x3F80, 0x3F80, 0x3F80};
    *(bf16x8*)&Vtlds[8 * 264 + tid * 8] = ones;
  }

  const bf16x8 zero8 = {0, 0, 0, 0, 0, 0, 0, 0};
  bf16x8 qb = zero8;
  if (quad == 0) qb = *(const bf16x8*)&Qbf[((size_t)h * MT + qbase + wid * 16 + n) * 8];

  f32x4 o_acc = {0.f, 0.f, 0.f, 0.f};

  for (int kt = 0; kt < 4; ++kt) {
    const int k0 = z * 1024 + kt * 256;
    __syncthreads();
    *(bf16x8*)&Klds[tid * 8] = *(const bf16x8*)&Kbf[((size_t)h * MT + k0 + tid) * 8];
    *(bf16x8*)&Vtlds[(tid >> 5) * 264 + (tid & 31) * 8] =
        *(const bf16x8*)&Vtb[((size_t)h * 8 + (tid >> 5)) * MT + k0 + (tid & 31) * 8];
    __syncthreads();

#pragma unroll
    for (int sub = 0; sub < 4; ++sub) {
      const short* kbase = &Klds[sub * 64 * 8];
      f32x4 s[4];
#pragma unroll
      for (int mt = 0; mt < 4; ++mt) {
        bf16x8 ka = zero8;
        if (quad == 0) ka = *(const bf16x8*)&kbase[(mt * 16 + n) * 8];
        f32x4 zf = {0.f, 0.f, 0.f, 0.f};
        s[mt] = __builtin_amdgcn_mfma_f32_16x16x32_bf16(ka, qb, zf, 0, 0, 0);
      }

      short* pw = &Plds[wid][n * 72 + quad * 4];
#pragma unroll
      for (int mt = 0; mt < 4; ++mt) {
        float p0 = __expf(s[mt][0]), p1 = __expf(s[mt][1]);
        float p2 = __expf(s[mt][2]), p3 = __expf(s[mt][3]);
        bf16x4 pv = {f2bf(p0), f2bf(p1), f2bf(p2), f2bf(p3)};
        *(bf16x4*)(pw + mt * 16) = pv;
      }

#pragma unroll
      for (int c = 0; c < 2; ++c) {
        bf16x8 va = zero8;
        if (n < 9) va = *(const bf16x8*)&Vtlds[n * 264 + sub * 64 + c * 32 + quad * 8];
        bf16x8 pb = *(const bf16x8*)&Plds[wid][n * 72 + c * 32 + quad * 8];
        o_acc = __builtin_amdgcn_mfma_f32_16x16x32_bf16(va, pb, o_acc, 0, 0, 0);
      }
    }
  }

  const int tok = qbase + wid * 16 + n;
  if (quad < 2) {
    float4 val = {o_acc[0], o_acc[1], o_acc[2], o_acc[3]};
    *(float4*)&pbuf[((size_t)z * MT + tok) * DM + h * 8 + quad * 4] = val;
  }
  if (quad == 2) lbuf[(size_t)z * MT * 8 + (size_t)tok * 8 + h] = o_acc[0];
}

// ---------------------------------------------------------------- fused dense layer
// 8 tokens/block, 256 threads. combine -> oproj+LN1 -> ff1 -> ff2+LN2 ->
// (qkv of next layer | final prune/norm/bf16)
__global__ __launch_bounds__(256) void dense_kernel(
    const float* __restrict__ pbuf, const float* __restrict__ lbuf,
    float* __restrict__ x,
    const float* __restrict__ Wto, const float* __restrict__ ob,
    const float* __restrict__ n1w, const float* __restrict__ n1b,
    const float* __restrict__ Wt1, const float* __restrict__ b1,
    const float* __restrict__ Wt2, const float* __restrict__ b2,
    const float* __restrict__ n2w, const float* __restrict__ n2b,
    const float* __restrict__ Wti, const float* __restrict__ inb,
    short* __restrict__ Qbf, short* __restrict__ Kbf, short* __restrict__ Vtb,
    int do_qkv,
    const float* __restrict__ mask, float* __restrict__ out,
    short* __restrict__ xmb, float* __restrict__ nrm, int do_final) {
  const int t0 = blockIdx.x * 8;
  const int tid = threadIdx.x;
  const int w = tid >> 6, d = tid & 63;

  __shared__ float orow[8][DM];
  __shared__ float x1[8][DM];
  __shared__ float fr[8][DFF];
  __shared__ float x2s[8][DM];

  // combine attention partials
#pragma unroll
  for (int tt = 0; tt < 2; ++tt) {
    const int t = w + tt * 4, tok = t0 + t, h = d >> 3;
    float o = 0.f, l = 0.f;
#pragma unroll
    for (int z = 0; z < 4; ++z) {
      o += pbuf[((size_t)z * MT + tok) * DM + d];
      l += lbuf[(size_t)z * MT * 8 + (size_t)tok * 8 + h];
    }
    orow[t][d] = o / l;
  }
  __syncthreads();

  // o-proj + residual + LN1
#pragma unroll
  for (int tt = 0; tt < 2; ++tt) {
    const int t = w + tt * 4, tok = t0 + t;
    float acc = ob[d];
#pragma unroll 8
    for (int k4 = 0; k4 < 16; ++k4) {
      float w0 = Wto[(k4 * 4 + 0) * 64 + d];
      float w1 = Wto[(k4 * 4 + 1) * 64 + d];
      float w2 = Wto[(k4 * 4 + 2) * 64 + d];
      float w3 = Wto[(k4 * 4 + 3) * 64 + d];
      float4 a = *(const float4*)&orow[t][k4 * 4];
      acc += a.x * w0 + a.y * w1 + a.z * w2 + a.w * w3;
    }
    float hv = x[(size_t)tok * DM + d] + acc;
    float mu = wave_sum64(hv) * (1.0f / DM);
    float dv = hv - mu;
    float var = wave_sum64(dv * dv) * (1.0f / DM);
    x1[t][d] = dv * rsqrtf(var + LN_EPS) * n1w[d] + n1b[d];
  }
  __syncthreads();

  // ff1 (thread = output o, all 8 tokens)
  {
    const int o = tid;
    float acc[8];
#pragma unroll
    for (int t = 0; t < 8; ++t) acc[t] = b1[o];
#pragma unroll 8
    for (int k4 = 0; k4 < 16; ++k4) {
      float w0 = Wt1[(k4 * 4 + 0) * 256 + o];
      float w1 = Wt1[(k4 * 4 + 1) * 256 + o];
      float w2 = Wt1[(k4 * 4 + 2) * 256 + o];
      float w3 = Wt1[(k4 * 4 + 3) * 256 + o];
#pragma unroll
      for (int t = 0; t < 8; ++t) {
        float4 a = *(const float4*)&x1[t][k4 * 4];
        acc[t] += a.x * w0 + a.y * w1 + a.z * w2 + a.w * w3;
      }
    }
#pragma unroll
    for (int t = 0; t < 8; ++t) fr[t][o] = fmaxf(acc[t], 0.0f);
  }
  __syncthreads();

  // ff2 + residual + LN2 (+ optional final prune/norm)
#pragma unroll
  for (int tt = 0; tt < 2; ++tt) {
    const int t = w + tt * 4, tok = t0 + t;
    float acc = b2[d];
#pragma unroll 8
    for (int k4 = 0; k4 < 64; ++k4) {
      float w0 = Wt2[(k4 * 4 + 0) * 64 + d];
      float w1 = Wt2[(k4 * 4 + 1) * 64 + d];
      float w2 = Wt2[(k4 * 4 + 2) * 64 + d];
      float w3 = Wt2[(k4 * 4 + 3) * 64 + d];
      float4 a = *(const float4*)&fr[t][k4 * 4];
      acc += a.x * w0 + a.y * w1 + a.z * w2 + a.w * w3;
    }
    float hv = x1[t][d] + acc;
    float mu = wave_sum64(hv) * (1.0f / DM);
    float dv = hv - mu;
    float var = wave_sum64(dv * dv) * (1.0f / DM);
    float v = dv * rsqrtf(var + LN_EPS) * n2w[d] + n2b[d];
    x2s[t][d] = v;
    x[(size_t)tok * DM + d] = v;
    if (do_final) {
      float pv = v * mask[d];
      out[(size_t)tok * DM + d] = pv;
      xmb[(size_t)tok * DM + d] = f2bf(pv);
      float s = wave_sum64(pv * pv);
      if (d == 0) nrm[tok] = s;
    }
  }
  __syncthreads();

  // qkv for next layer
  if (do_qkv) {
#pragma unroll
    for (int j = 0; j < 6; ++j) {
      const int flat = j * 256 + tid;           // 0..1535 = 8 tokens x 192 outs
      const int t = flat / 192, o = flat % 192;
      const int tok = t0 + t;
      float acc = inb[o];
#pragma unroll 8
      for (int k4 = 0; k4 < 16; ++k4) {
        float w0 = Wti[(k4 * 4 + 0) * 192 + o];
        float w1 = Wti[(k4 * 4 + 1) * 192 + o];
        float w2 = Wti[(k4 * 4 + 2) * 192 + o];
        float w3 = Wti[(k4 * 4 + 3) * 192 + o];
        float4 a = *(const float4*)&x2s[t][k4 * 4];
        acc += a.x * w0 + a.y * w1 + a.z * w2 + a.w * w3;
      }
      if (o < 64) {
        Qbf[(((size_t)(o >> 3)) * MT + tok) * 8 + (o & 7)] = f2bf(acc * 0.35355339059327373f);
      } else if (o < 128) {
        const int c = o - 64;
        Kbf[(((size_t)(c >> 3)) * MT + tok) * 8 + (c & 7)] = f2bf(acc);
      } else {
        Vtb[(size_t)(o - 128) * MT + tok] = f2bf(acc);
      }
    }
  }
}

// ---------------------------------------------------------------- MMD via MFMA, 128x128 tiles
// grid (32,32,3); block 256 (4 waves). Wave handles 32 A-rows (2 strips),
// loops 8 B-strips; 32 mfma/wave. All loads direct from bf16 global (L1/L2).
__global__ __launch_bounds__(256) void mmd_kernel(const short* __restrict__ xmb,
                                                  const short* __restrict__ rgbb,
                                                  const float* __restrict__ nrm,
                                                  float* __restrict__ partials) {
  const int p = blockIdx.z;
  const short* A = (p == 1) ? rgbb : xmb;
  const short* B = (p == 0) ? xmb : rgbb;
  const float* nA = (p == 1) ? (nrm + MT) : nrm;
  const float* nB = (p == 0) ? nrm : (nrm + MT);
  const int i0 = blockIdx.x * 128;
  const int j0 = blockIdx.y * 128;
  const int tid = threadIdx.x;
  const int wid = tid >> 6;
  const int lane = tid & 63;
  const int n = lane & 15;
  const int quad = lane >> 4;

  bf16x8 a0[2], a1[2];
  float na[2][4];
#pragma unroll
  for (int s = 0; s < 2; ++s) {
    const int arow = i0 + wid * 32 + s * 16 + n;
    a0[s] = *(const bf16x8*)&A[(size_t)arow * DM + quad * 8];
    a1[s] = *(const bf16x8*)&A[(size_t)arow * DM + 32 + quad * 8];
#pragma unroll
    for (int r = 0; r < 4; ++r) na[s][r] = nA[i0 + wid * 32 + s * 16 + quad * 4 + r];
  }

  float local = 0.f;
#pragma unroll
  for (int nt = 0; nt < 8; ++nt) {
    const int brow = j0 + nt * 16 + n;
    bf16x8 b0 = *(const bf16x8*)&B[(size_t)brow * DM + quad * 8];
    bf16x8 b1 = *(const bf16x8*)&B[(size_t)brow * DM + 32 + quad * 8];
    float nb = nB[j0 + nt * 16 + n];
#pragma unroll
    for (int s = 0; s < 2; ++s) {
      f32x4 zf = {0.f, 0.f, 0.f, 0.f};
      f32x4 d4 = __builtin_amdgcn_mfma_f32_16x16x32_bf16(a0[s], b0, zf, 0, 0, 0);
      d4 = __builtin_amdgcn_mfma_f32_16x16x32_bf16(a1[s], b1, d4, 0, 0, 0);
#pragma unroll
      for (int r = 0; r < 4; ++r) {
        float dist = na[s][r] + nb - 2.0f * d4[r];
        local += __expf(-0.5f * dist);
      }
    }
  }

  float tot = wave_sum64(local);
  __shared__ float wpart[4];
  if (lane == 0) wpart[wid] = tot;
  __syncthreads();
  if (tid == 0)
    partials[(size_t)p * 1024 + blockIdx.y * 32 + blockIdx.x] =
        wpart[0] + wpart[1] + wpart[2] + wpart[3];
}

// ---------------------------------------------------------------- reduce + finalize
__global__ __launch_bounds__(256) void reducefin_kernel(const float* __restrict__ partials,
                                                        float* __restrict__ out) {
  const int w = threadIdx.x >> 6, lane = threadIdx.x & 63;
  __shared__ float L[4];
  float s = 0.f;
  if (w < 3)
    for (int i = lane; i < 1024; i += 64) s += partials[(size_t)w * 1024 + i];
  s = wave_sum64(s);
  if (lane == 0) L[w] = s;
  __syncthreads();
  if (threadIdx.x == 0) {
    const float invn = 1.0f / ((float)MT * (float)MT);
    out[(size_t)MT * DM] = (L[0] + L[1] - 2.0f * L[2]) * invn;
  }
}

// ================================================================ launcher
extern "C" void kernel_launch(void* const* d_in, const int* in_sizes, int n_in,
                              void* d_out, int out_size, void* d_ws, size_t ws_size,
                              hipStream_t stream) {
  const float* hsi  = (const float*)d_in[0];
  const float* rgb  = (const float*)d_in[1];
  const float* inw  = (const float*)d_in[2];
  const float* inb  = (const float*)d_in[3];
  const float* ow   = (const float*)d_in[4];
  const float* obv  = (const float*)d_in[5];
  const float* l1w  = (const float*)d_in[6];
  const float* l1b  = (const float*)d_in[7];
  const float* l2w  = (const float*)d_in[8];
  const float* l2b  = (const float*)d_in[9];
  const float* n1w  = (const float*)d_in[10];
  const float* n1b  = (const float*)d_in[11];
  const float* n2w  = (const float*)d_in[12];
  const float* n2b  = (const float*)d_in[13];
  const float* mask = (const float*)d_in[14];
  float* out = (float*)d_out;

  float* ws    = (float*)d_ws;
  float* x     = ws;                        // 262144
  float* pbuf  = ws + 262144;               // 4 * 262144
  float* lbuf  = ws + 1310720;              // 4 * 32768
  float* nrm   = ws + 1441792;              // 8192
  float* parts = ws + 1449984;              // 3072
  float* Wti   = ws + 1453056;              // 49152
  float* Wto   = ws + 1502208;              // 16384
  float* Wt1   = ws + 1518592;              // 65536
  float* Wt2   = ws + 1584128;              // 65536
  short* xmb   = (short*)(ws + 1649664);    // 262144 shorts
  short* rgbb  = (short*)(ws + 1780736);    // 262144 shorts
  short* Qbf   = (short*)(ws + 1911808);    // 262144 shorts
  short* Kbf   = (short*)(ws + 2042880);    // 262144 shorts
  short* Vtb   = (short*)(ws + 2173952);    // 262144 shorts (end 2305024 floats ~9.2MB)

  prep_kernel<<<192 + MT / 4, 256, 0, stream>>>(inw, Wti, ow, Wto, l1w, Wt1, l2w, Wt2,
                                                rgb, rgbb, nrm);
  qkv0_kernel<<<MT / 4, 192, 0, stream>>>(hsi, Wti, inb, x, Qbf, Kbf, Vtb);

  for (int i = 0; i < NLAYER; ++i) {
    attn_kernel<<<dim3(MT / 64, NHEAD, 4), 256, 0, stream>>>(Qbf, Kbf, Vtb, pbuf, lbuf);
    const int last = (i == NLAYER - 1);
    dense_kernel<<<MT / 8, 256, 0, stream>>>(
        pbuf, lbuf, x,
        Wto + (size_t)i * DM * DM, obv + (size_t)i * DM,
        n1w + (size_t)i * DM, n1b + (size_t)i * DM,
        Wt1 + (size_t)i * DFF * DM, l1b + (size_t)i * DFF,
        Wt2 + (size_t)i * DM * DFF, l2b + (size_t)i * DM,
        n2w + (size_t)i * DM, n2b + (size_t)i * DM,
        Wti + (size_t)(last ? 0 : (i + 1)) * 192 * DM,
        inb + (size_t)(last ? 0 : (i + 1)) * 192,
        Qbf, Kbf, Vtb, !last,
        mask, out, xmb, nrm, last);
  }

  mmd_kernel<<<dim3(32, 32, 3), 256, 0, stream>>>(xmb, rgbb, nrm, parts);
  reducefin_kernel<<<1, 256, 0, stream>>>(parts, out);
}

// Round 8
// 355.006 us; speedup vs baseline: 6.4127x; 1.0574x over previous
//
#include <hip/hip_runtime.h>

#define MT 4096      // tokens
#define DM 64        // d_model
#define NHEAD 8
#define HDIM 8
#define DFF 256
#define NLAYER 4
#define LN_EPS 1e-5f

typedef __attribute__((ext_vector_type(8))) short bf16x8;
typedef __attribute__((ext_vector_type(4))) short bf16x4;
typedef __attribute__((ext_vector_type(4))) float f32x4;

__device__ __forceinline__ float wave_sum64(float v) {
#pragma unroll
  for (int m = 1; m < 64; m <<= 1) v += __shfl_xor(v, m, 64);
  return v;
}

__device__ __forceinline__ short f2bf(float x) {   // RNE float->bf16
  union { float f; unsigned u; } v; v.f = x;
  unsigned r = v.u + 0x7fffu + ((v.u >> 16) & 1u);
  return (short)(r >> 16);
}

__device__ __forceinline__ unsigned pack2_trunc(float a, float b) {  // [bf16(a),bf16(b)] truncated
  union { float f; unsigned u; } x, y; x.f = a; y.f = b;
  return (x.u >> 16) | (y.u & 0xFFFF0000u);
}

// ---------------------------------------------------------------- prep: weight k4-pack + rgb prep
// Packed layout: W4[k4][o][j] (j=0..3, k=k4*4+j) -> one dwordx4 per k4 per output.
// bid<192: weight tiles; bid>=192: rgb rows -> rgbb + nrm[MT..2MT)
__global__ void prep_kernel(const float* __restrict__ inw, float* __restrict__ Wti,
                            const float* __restrict__ ow,  float* __restrict__ Wto,
                            const float* __restrict__ l1w, float* __restrict__ Wt1,
                            const float* __restrict__ l2w, float* __restrict__ Wt2,
                            const float* __restrict__ rgb, short* __restrict__ rgbb,
                            float* __restrict__ nrm) {
  const int bid = blockIdx.x;
  const int tid = threadIdx.x;
  if (bid >= 192) {
    const int row = (bid - 192) * 4 + (tid >> 6);
    const int d = tid & 63;
    float v = rgb[(size_t)row * DM + d];
    rgbb[(size_t)row * DM + d] = f2bf(v);
    float s = wave_sum64(v * v);
    if (d == 0) nrm[MT + row] = s;
    return;
  }
  const float* src; float* dst; int R, C, r0, c0;
  if (bid < 48) {
    int l = bid / 12, t = bid % 12;
    src = inw + (size_t)l * 12288; dst = Wti + (size_t)l * 12288;
    R = 192; C = 64; c0 = (t % 2) * 32; r0 = (t / 2) * 32;
  } else if (bid < 64) {
    int idx = bid - 48, l = idx / 4, t = idx % 4;
    src = ow + (size_t)l * 4096; dst = Wto + (size_t)l * 4096;
    R = 64; C = 64; c0 = (t % 2) * 32; r0 = (t / 2) * 32;
  } else if (bid < 128) {
    int idx = bid - 64, l = idx / 16, t = idx % 16;
    src = l1w + (size_t)l * 16384; dst = Wt1 + (size_t)l * 16384;
    R = 256; C = 64; c0 = (t % 2) * 32; r0 = (t / 2) * 32;
  } else {
    int idx = bid - 128, l = idx / 16, t = idx % 16;
    src = l2w + (size_t)l * 16384; dst = Wt2 + (size_t)l * 16384;
    R = 64; C = 256; c0 = (t % 8) * 32; r0 = (t / 8) * 32;
  }
  __shared__ float tl[32][33];
  const int tx = tid & 31, ty = tid >> 5;
  for (int rr = ty; rr < 32; rr += 8)
    tl[rr][tx] = src[(size_t)(r0 + rr) * C + c0 + tx];
  __syncthreads();
  // write packed: dst[((c0/4 + k4l)*R + r0 + ol)*4 + j] = tl[ol][k4l*4+j]
  for (int idx = tid; idx < 1024; idx += 256) {
    const int k4l = idx >> 7, rem = idx & 127, ol = rem >> 2, j = rem & 3;
    dst[(((size_t)(c0 >> 2) + k4l) * R + r0 + ol) * 4 + j] = tl[ol][k4l * 4 + j];
  }
}

// ---------------------------------------------------------------- layer-0 qkv from hsi (+ x copy)
// Wt packed [k4][192][4]
__global__ __launch_bounds__(192) void qkv0_kernel(const float* __restrict__ hsi,
                                                   const float* __restrict__ Wt,
                                                   const float* __restrict__ B,
                                                   float* __restrict__ x,
                                                   short* __restrict__ Qbf,
                                                   short* __restrict__ Kbf,
                                                   short* __restrict__ Vtb) {
  const int t0 = blockIdx.x * 4;
  const int o = threadIdx.x;
  __shared__ float xr[4][DM];
  for (int e = o; e < 64; e += 192) {
    float4 v = ((const float4*)(hsi + (size_t)t0 * DM))[e];
    ((float4*)xr)[e] = v;
    ((float4*)(x + (size_t)t0 * DM))[e] = v;
  }
  __syncthreads();
  float acc0 = B[o], acc1 = acc0, acc2 = acc0, acc3 = acc0;
#pragma unroll 8
  for (int k4 = 0; k4 < 16; ++k4) {
    float4 w4 = ((const float4*)Wt)[k4 * 192 + o];
    float4 a = *(const float4*)&xr[0][k4 * 4];
    acc0 += a.x * w4.x + a.y * w4.y + a.z * w4.z + a.w * w4.w;
    float4 b = *(const float4*)&xr[1][k4 * 4];
    acc1 += b.x * w4.x + b.y * w4.y + b.z * w4.z + b.w * w4.w;
    float4 c = *(const float4*)&xr[2][k4 * 4];
    acc2 += c.x * w4.x + c.y * w4.y + c.z * w4.z + c.w * w4.w;
    float4 d = *(const float4*)&xr[3][k4 * 4];
    acc3 += d.x * w4.x + d.y * w4.y + d.z * w4.z + d.w * w4.w;
  }
  if (o < 128) {
    const int c = o & 63, hh = c >> 3, ch = c & 7;
    short* dst = (o < 64) ? Qbf : Kbf;
    const float sc = (o < 64) ? 0.35355339059327373f : 1.0f;
    dst[((size_t)hh * MT + t0 + 0) * 8 + ch] = f2bf(acc0 * sc);
    dst[((size_t)hh * MT + t0 + 1) * 8 + ch] = f2bf(acc1 * sc);
    dst[((size_t)hh * MT + t0 + 2) * 8 + ch] = f2bf(acc2 * sc);
    dst[((size_t)hh * MT + t0 + 3) * 8 + ch] = f2bf(acc3 * sc);
  } else {
    const int c = o - 128;
    bf16x4 v = {f2bf(acc0), f2bf(acc1), f2bf(acc2), f2bf(acc3)};
    *(bf16x4*)&Vtb[(size_t)c * MT + t0] = v;
  }
}

// ---------------------------------------------------------------- MFMA flash attention, no-max, z=4
// Double-buffered K/V staging: one barrier per 256-key tile, prefetch overlap.
__global__ __launch_bounds__(256) void attn_kernel(const short* __restrict__ Qbf,
                                                   const short* __restrict__ Kbf,
                                                   const short* __restrict__ Vtb,
                                                   float* __restrict__ pbuf,
                                                   float* __restrict__ lbuf) {
  const int h = blockIdx.y;
  const int qbase = blockIdx.x * 64;
  const int z = blockIdx.z;
  const int tid = threadIdx.x;
  const int wid = tid >> 6;
  const int lane = tid & 63;
  const int n = lane & 15;
  const int quad = lane >> 4;

  __shared__ short Klds[2][256 * 8];
  __shared__ short Vtlds[2][9 * 264];
  __shared__ short Plds[4][16 * 72];

  if (tid < 32) {
    bf16x8 ones = {0x3F80, 0x3F80, 0x3F80, 0x3F80, 0x3F80, 0x3F80, 0x3F80, 0x3F80};
    *(bf16x8*)&Vtlds[0][8 * 264 + tid * 8] = ones;
    *(bf16x8*)&Vtlds[1][8 * 264 + tid * 8] = ones;
  }

  const bf16x8 zero8 = {0, 0, 0, 0, 0, 0, 0, 0};
  bf16x8 qb = zero8;
  if (quad == 0) qb = *(const bf16x8*)&Qbf[((size_t)h * MT + qbase + wid * 16 + n) * 8];

  // stage tile 0
  {
    const int k0 = z * 1024;
    *(bf16x8*)&Klds[0][tid * 8] = *(const bf16x8*)&Kbf[((size_t)h * MT + k0 + tid) * 8];
    *(bf16x8*)&Vtlds[0][(tid >> 5) * 264 + (tid & 31) * 8] =
        *(const bf16x8*)&Vtb[((size_t)h * 8 + (tid >> 5)) * MT + k0 + (tid & 31) * 8];
  }
  __syncthreads();

  f32x4 o_acc = {0.f, 0.f, 0.f, 0.f};

  for (int kt = 0; kt < 4; ++kt) {
    const int buf = kt & 1;
    if (kt < 3) {
      const int k1 = z * 1024 + (kt + 1) * 256;
      *(bf16x8*)&Klds[buf ^ 1][tid * 8] = *(const bf16x8*)&Kbf[((size_t)h * MT + k1 + tid) * 8];
      *(bf16x8*)&Vtlds[buf ^ 1][(tid >> 5) * 264 + (tid & 31) * 8] =
          *(const bf16x8*)&Vtb[((size_t)h * 8 + (tid >> 5)) * MT + k1 + (tid & 31) * 8];
    }

#pragma unroll
    for (int sub = 0; sub < 4; ++sub) {
      const short* kbase = &Klds[buf][sub * 64 * 8];
      f32x4 s[4];
#pragma unroll
      for (int mt = 0; mt < 4; ++mt) {
        bf16x8 ka = zero8;
        if (quad == 0) ka = *(const bf16x8*)&kbase[(mt * 16 + n) * 8];
        f32x4 zf = {0.f, 0.f, 0.f, 0.f};
        s[mt] = __builtin_amdgcn_mfma_f32_16x16x32_bf16(ka, qb, zf, 0, 0, 0);
      }

      short* pw = &Plds[wid][n * 72 + quad * 4];
#pragma unroll
      for (int mt = 0; mt < 4; ++mt) {
        unsigned lo = pack2_trunc(__expf(s[mt][0]), __expf(s[mt][1]));
        unsigned hi = pack2_trunc(__expf(s[mt][2]), __expf(s[mt][3]));
        uint2 pv = {lo, hi};
        *(uint2*)(pw + mt * 16) = pv;
      }

#pragma unroll
      for (int c = 0; c < 2; ++c) {
        bf16x8 va = zero8;
        if (n < 9) va = *(const bf16x8*)&Vtlds[buf][n * 264 + sub * 64 + c * 32 + quad * 8];
        bf16x8 pb = *(const bf16x8*)&Plds[wid][n * 72 + c * 32 + quad * 8];
        o_acc = __builtin_amdgcn_mfma_f32_16x16x32_bf16(va, pb, o_acc, 0, 0, 0);
      }
    }
    __syncthreads();
  }

  const int tok = qbase + wid * 16 + n;
  if (quad < 2) {
    float4 val = {o_acc[0], o_acc[1], o_acc[2], o_acc[3]};
    *(float4*)&pbuf[((size_t)z * MT + tok) * DM + h * 8 + quad * 4] = val;
  }
  if (quad == 2) lbuf[(size_t)z * MT * 8 + (size_t)tok * 8 + h] = o_acc[0];
}

// ---------------------------------------------------------------- fused dense layer (packed weights)
__global__ __launch_bounds__(256) void dense_kernel(
    const float* __restrict__ pbuf, const float* __restrict__ lbuf,
    float* __restrict__ x,
    const float* __restrict__ Wto, const float* __restrict__ ob,
    const float* __restrict__ n1w, const float* __restrict__ n1b,
    const float* __restrict__ Wt1, const float* __restrict__ b1,
    const float* __restrict__ Wt2, const float* __restrict__ b2,
    const float* __restrict__ n2w, const float* __restrict__ n2b,
    const float* __restrict__ Wti, const float* __restrict__ inb,
    short* __restrict__ Qbf, short* __restrict__ Kbf, short* __restrict__ Vtb,
    int do_qkv,
    const float* __restrict__ mask, float* __restrict__ out,
    short* __restrict__ xmb, float* __restrict__ nrm, int do_final) {
  const int t0 = blockIdx.x * 8;
  const int tid = threadIdx.x;
  const int w = tid >> 6, d = tid & 63;

  __shared__ float orow[8][DM];
  __shared__ float x1[8][DM];
  __shared__ float fr[8][DFF];
  __shared__ float x2s[8][DM];

  // combine attention partials
#pragma unroll
  for (int tt = 0; tt < 2; ++tt) {
    const int t = w + tt * 4, tok = t0 + t, h = d >> 3;
    float o = 0.f, l = 0.f;
#pragma unroll
    for (int z = 0; z < 4; ++z) {
      o += pbuf[((size_t)z * MT + tok) * DM + d];
      l += lbuf[(size_t)z * MT * 8 + (size_t)tok * 8 + h];
    }
    orow[t][d] = o / l;
  }
  __syncthreads();

  // o-proj + residual + LN1
#pragma unroll
  for (int tt = 0; tt < 2; ++tt) {
    const int t = w + tt * 4, tok = t0 + t;
    float acc = ob[d];
#pragma unroll 8
    for (int k4 = 0; k4 < 16; ++k4) {
      float4 w4 = ((const float4*)Wto)[k4 * 64 + d];
      float4 a = *(const float4*)&orow[t][k4 * 4];
      acc += a.x * w4.x + a.y * w4.y + a.z * w4.z + a.w * w4.w;
    }
    float hv = x[(size_t)tok * DM + d] + acc;
    float mu = wave_sum64(hv) * (1.0f / DM);
    float dv = hv - mu;
    float var = wave_sum64(dv * dv) * (1.0f / DM);
    x1[t][d] = dv * rsqrtf(var + LN_EPS) * n1w[d] + n1b[d];
  }
  __syncthreads();

  // ff1 (thread = output o, all 8 tokens)
  {
    const int o = tid;
    float acc[8];
#pragma unroll
    for (int t = 0; t < 8; ++t) acc[t] = b1[o];
#pragma unroll 8
    for (int k4 = 0; k4 < 16; ++k4) {
      float4 w4 = ((const float4*)Wt1)[k4 * 256 + o];
#pragma unroll
      for (int t = 0; t < 8; ++t) {
        float4 a = *(const float4*)&x1[t][k4 * 4];
        acc[t] += a.x * w4.x + a.y * w4.y + a.z * w4.z + a.w * w4.w;
      }
    }
#pragma unroll
    for (int t = 0; t < 8; ++t) fr[t][o] = fmaxf(acc[t], 0.0f);
  }
  __syncthreads();

  // ff2 + residual + LN2 (+ optional final prune/norm)
#pragma unroll
  for (int tt = 0; tt < 2; ++tt) {
    const int t = w + tt * 4, tok = t0 + t;
    float acc = b2[d];
#pragma unroll 8
    for (int k4 = 0; k4 < 64; ++k4) {
      float4 w4 = ((const float4*)Wt2)[k4 * 64 + d];
      float4 a = *(const float4*)&fr[t][k4 * 4];
      acc += a.x * w4.x + a.y * w4.y + a.z * w4.z + a.w * w4.w;
    }
    float hv = x1[t][d] + acc;
    float mu = wave_sum64(hv) * (1.0f / DM);
    float dv = hv - mu;
    float var = wave_sum64(dv * dv) * (1.0f / DM);
    float v = dv * rsqrtf(var + LN_EPS) * n2w[d] + n2b[d];
    x2s[t][d] = v;
    x[(size_t)tok * DM + d] = v;
    if (do_final) {
      float pv = v * mask[d];
      out[(size_t)tok * DM + d] = pv;
      xmb[(size_t)tok * DM + d] = f2bf(pv);
      float s = wave_sum64(pv * pv);
      if (d == 0) nrm[tok] = s;
    }
  }
  __syncthreads();

  // qkv for next layer
  if (do_qkv) {
#pragma unroll
    for (int j = 0; j < 6; ++j) {
      const int flat = j * 256 + tid;           // 0..1535 = 8 tokens x 192 outs
      const int t = flat / 192, o = flat % 192;
      const int tok = t0 + t;
      float acc = inb[o];
#pragma unroll 8
      for (int k4 = 0; k4 < 16; ++k4) {
        float4 w4 = ((const float4*)Wti)[k4 * 192 + o];
        float4 a = *(const float4*)&x2s[t][k4 * 4];
        acc += a.x * w4.x + a.y * w4.y + a.z * w4.z + a.w * w4.w;
      }
      if (o < 64) {
        Qbf[(((size_t)(o >> 3)) * MT + tok) * 8 + (o & 7)] = f2bf(acc * 0.35355339059327373f);
      } else if (o < 128) {
        const int c = o - 64;
        Kbf[(((size_t)(c >> 3)) * MT + tok) * 8 + (c & 7)] = f2bf(acc);
      } else {
        Vtb[(size_t)(o - 128) * MT + tok] = f2bf(acc);
      }
    }
  }
}

// ---------------------------------------------------------------- MMD via MFMA, 128x128 tiles
__global__ __launch_bounds__(256) void mmd_kernel(const short* __restrict__ xmb,
                                                  const short* __restrict__ rgbb,
                                                  const float* __restrict__ nrm,
                                                  float* __restrict__ partials) {
  const int p = blockIdx.z;
  const short* A = (p == 1) ? rgbb : xmb;
  const short* B = (p == 0) ? xmb : rgbb;
  const float* nA = (p == 1) ? (nrm + MT) : nrm;
  const float* nB = (p == 0) ? nrm : (nrm + MT);
  const int i0 = blockIdx.x * 128;
  const int j0 = blockIdx.y * 128;
  const int tid = threadIdx.x;
  const int wid = tid >> 6;
  const int lane = tid & 63;
  const int n = lane & 15;
  const int quad = lane >> 4;

  bf16x8 a0[2], a1[2];
  float na[2][4];
#pragma unroll
  for (int s = 0; s < 2; ++s) {
    const int arow = i0 + wid * 32 + s * 16 + n;
    a0[s] = *(const bf16x8*)&A[(size_t)arow * DM + quad * 8];
    a1[s] = *(const bf16x8*)&A[(size_t)arow * DM + 32 + quad * 8];
#pragma unroll
    for (int r = 0; r < 4; ++r) na[s][r] = nA[i0 + wid * 32 + s * 16 + quad * 4 + r];
  }

  float local = 0.f;
#pragma unroll
  for (int nt = 0; nt < 8; ++nt) {
    const int brow = j0 + nt * 16 + n;
    bf16x8 b0 = *(const bf16x8*)&B[(size_t)brow * DM + quad * 8];
    bf16x8 b1 = *(const bf16x8*)&B[(size_t)brow * DM + 32 + quad * 8];
    float nb = nB[j0 + nt * 16 + n];
#pragma unroll
    for (int s = 0; s < 2; ++s) {
      f32x4 zf = {0.f, 0.f, 0.f, 0.f};
      f32x4 d4 = __builtin_amdgcn_mfma_f32_16x16x32_bf16(a0[s], b0, zf, 0, 0, 0);
      d4 = __builtin_amdgcn_mfma_f32_16x16x32_bf16(a1[s], b1, d4, 0, 0, 0);
#pragma unroll
      for (int r = 0; r < 4; ++r) {
        float dist = na[s][r] + nb - 2.0f * d4[r];
        local += __expf(-0.5f * dist);
      }
    }
  }

  float tot = wave_sum64(local);
  __shared__ float wpart[4];
  if (lane == 0) wpart[wid] = tot;
  __syncthreads();
  if (tid == 0)
    partials[(size_t)p * 1024 + blockIdx.y * 32 + blockIdx.x] =
        wpart[0] + wpart[1] + wpart[2] + wpart[3];
}

// ---------------------------------------------------------------- reduce + finalize
__global__ __launch_bounds__(256) void reducefin_kernel(const float* __restrict__ partials,
                                                        float* __restrict__ out) {
  const int w = threadIdx.x >> 6, lane = threadIdx.x & 63;
  __shared__ float L[4];
  float s = 0.f;
  if (w < 3)
    for (int i = lane; i < 1024; i += 64) s += partials[(size_t)w * 1024 + i];
  s = wave_sum64(s);
  if (lane == 0) L[w] = s;
  __syncthreads();
  if (threadIdx.x == 0) {
    const float invn = 1.0f / ((float)MT * (float)MT);
    out[(size_t)MT * DM] = (L[0] + L[1] - 2.0f * L[2]) * invn;
  }
}

// ================================================================ launcher
extern "C" void kernel_launch(void* const* d_in, const int* in_sizes, int n_in,
                              void* d_out, int out_size, void* d_ws, size_t ws_size,
                              hipStream_t stream) {
  const float* hsi  = (const float*)d_in[0];
  const float* rgb  = (const float*)d_in[1];
  const float* inw  = (const float*)d_in[2];
  const float* inb  = (const float*)d_in[3];
  const float* ow   = (const float*)d_in[4];
  const float* obv  = (const float*)d_in[5];
  const float* l1w  = (const float*)d_in[6];
  const float* l1b  = (const float*)d_in[7];
  const float* l2w  = (const float*)d_in[8];
  const float* l2b  = (const float*)d_in[9];
  const float* n1w  = (const float*)d_in[10];
  const float* n1b  = (const float*)d_in[11];
  const float* n2w  = (const float*)d_in[12];
  const float* n2b  = (const float*)d_in[13];
  const float* mask = (const float*)d_in[14];
  float* out = (float*)d_out;

  float* ws    = (float*)d_ws;
  float* x     = ws;                        // 262144
  float* pbuf  = ws + 262144;               // 4 * 262144
  float* lbuf  = ws + 1310720;              // 4 * 32768
  float* nrm   = ws + 1441792;              // 8192
  float* parts = ws + 1449984;              // 3072
  float* Wti   = ws + 1453056;              // 49152 (packed)
  float* Wto   = ws + 1502208;              // 16384
  float* Wt1   = ws + 1518592;              // 65536
  float* Wt2   = ws + 1584128;              // 65536
  short* xmb   = (short*)(ws + 1649664);    // 262144 shorts
  short* rgbb  = (short*)(ws + 1780736);    // 262144 shorts
  short* Qbf   = (short*)(ws + 1911808);    // 262144 shorts
  short* Kbf   = (short*)(ws + 2042880);    // 262144 shorts
  short* Vtb   = (short*)(ws + 2173952);    // 262144 shorts

  prep_kernel<<<192 + MT / 4, 256, 0, stream>>>(inw, Wti, ow, Wto, l1w, Wt1, l2w, Wt2,
                                                rgb, rgbb, nrm);
  qkv0_kernel<<<MT / 4, 192, 0, stream>>>(hsi, Wti, inb, x, Qbf, Kbf, Vtb);

  for (int i = 0; i < NLAYER; ++i) {
    attn_kernel<<<dim3(MT / 64, NHEAD, 4), 256, 0, stream>>>(Qbf, Kbf, Vtb, pbuf, lbuf);
    const int last = (i == NLAYER - 1);
    dense_kernel<<<MT / 8, 256, 0, stream>>>(
        pbuf, lbuf, x,
        Wto + (size_t)i * DM * DM, obv + (size_t)i * DM,
        n1w + (size_t)i * DM, n1b + (size_t)i * DM,
        Wt1 + (size_t)i * DFF * DM, l1b + (size_t)i * DFF,
        Wt2 + (size_t)i * DM * DFF, l2b + (size_t)i * DM,
        n2w + (size_t)i * DM, n2b + (size_t)i * DM,
        Wti + (size_t)(last ? 0 : (i + 1)) * 192 * DM,
        inb + (size_t)(last ? 0 : (i + 1)) * 192,
        Qbf, Kbf, Vtb, !last,
        mask, out, xmb, nrm, last);
  }

  mmd_kernel<<<dim3(32, 32, 3), 256, 0, stream>>>(xmb, rgbb, nrm, parts);
  reducefin_kernel<<<1, 256, 0, stream>>>(parts, out);
}